// Round 7
// baseline (1764.871 us; speedup 1.0000x reference)
//
#include <hip/hip_runtime.h>
#include <stdint.h>

typedef uint16_t u16;
typedef uint32_t u32;

#define DEVI __device__ __forceinline__

DEVI float b2f(u16 u) { return __uint_as_float(((u32)u) << 16); }
DEVI float blo(u32 u) { return __uint_as_float(u << 16); }
DEVI float bhi(u32 u) { return __uint_as_float(u & 0xffff0000u); }
DEVI u16 f2b(float f) {
  u32 x = __float_as_uint(f);
  return (u16)((x + 0x7fffu + ((x >> 16) & 1u)) >> 16);
}
DEVI u32 pack2(float a, float b) { return (u32)f2b(a) | ((u32)f2b(b) << 16); }
DEVI float sigm(float x) { return 1.f / (1.f + __expf(-x)); }
// fast tanh: exact at +-inf, ~1e-6 rel error (bf16 output rounds at 2^-8)
DEVI float ftanh(float x) { return 1.f - 2.f / (1.f + __expf(2.f * x)); }

typedef __bf16 bf16x8 __attribute__((ext_vector_type(8)));
typedef float f32x4 __attribute__((ext_vector_type(4)));

#define MFMA16(a, b, c) __builtin_amdgcn_mfma_f32_16x16x32_bf16(a, b, c, 0, 0, 0)

DEVI void gll16(const void* g, void* l) {
  __builtin_amdgcn_global_load_lds((const __attribute__((address_space(1))) void*)g,
                                   (__attribute__((address_space(3))) void*)l, 16, 0, 0);
}

// monotonic total-order map for f32 bits
DEVI u32 fmono(float s) {
  u32 x = __float_as_uint(s);
  return x ^ (((u32)((int)x >> 31)) | 0x80000000u);
}

// descending compare-exchange (max to lower index)
DEVI void ced(u32& a, u32& b) {
  u32 hi = max(a, b), lo = min(a, b);
  a = hi; b = lo;
}
// Batcher odd-even merge sort, 8 elems, descending (19 CE)
DEVI void sort8_desc(u32* v) {
  ced(v[0], v[1]); ced(v[2], v[3]); ced(v[4], v[5]); ced(v[6], v[7]);
  ced(v[0], v[2]); ced(v[1], v[3]); ced(v[4], v[6]); ced(v[5], v[7]);
  ced(v[1], v[2]); ced(v[5], v[6]);
  ced(v[0], v[4]); ced(v[1], v[5]); ced(v[2], v[6]); ced(v[3], v[7]);
  ced(v[2], v[4]); ced(v[3], v[5]);
  ced(v[1], v[2]); ced(v[3], v[4]); ced(v[5], v[6]);
}
// bitonic 8-sequence -> descending sorted (12 CE)
DEVI void bitonic8_desc(u32* v) {
  ced(v[0], v[4]); ced(v[1], v[5]); ced(v[2], v[6]); ced(v[3], v[7]);
  ced(v[0], v[2]); ced(v[1], v[3]); ced(v[4], v[6]); ced(v[5], v[7]);
  ced(v[0], v[1]); ced(v[2], v[3]); ced(v[4], v[5]); ced(v[6], v[7]);
}
// a,b desc-sorted 8-lists -> a = top-8 of union, desc sorted
DEVI void merge_top8(u32* a, const u32* b) {
#pragma unroll
  for (int j = 0; j < 8; ++j) a[j] = max(a[j], b[7 - j]);
  bitonic8_desc(a);
}

// ---------------- input dtype detect: 0 = bf16, 1 = fp32 ----------------
__global__ void detect_kernel(const u16* __restrict__ x, int* __restrict__ flag) {
  if (threadIdx.x == 0 && blockIdx.x == 0) {
    int f = 0;
    for (int i = 0; i < 64; ++i) {
      u16 u = x[2 * i];  // low half if fp32
      int e = (u >> 7) & 0xFF;
      if (e > 131) f = 1;  // |val| >= 32 impossible for randn bf16
    }
    *flag = f;
  }
}

// ---------------- fused convert: all inputs -> bf16 arena, one dispatch ----------------
struct CvtArgs {
  const void* src[23];
  int aoff[23];
  int n[23];
  int total;
};

__global__ __launch_bounds__(256) void convert_fused(CvtArgs a, u16* __restrict__ arena,
                                                     const int* __restrict__ flag) {
  int e4 = (blockIdx.x * 256 + threadIdx.x) * 4;
  if (e4 >= a.total) return;
  const char* sp = (const char*)a.src[0];
  int rel = e4, cnt = a.n[0];
#pragma unroll
  for (int j = 1; j < 23; ++j)
    if (e4 >= a.aoff[j]) { sp = (const char*)a.src[j]; rel = e4 - a.aoff[j]; cnt = a.n[j]; }
  const bool f32 = (*flag != 0);
  if (rel + 3 < cnt) {
    if (f32) {
      float4 v = *(const float4*)(sp + (size_t)rel * 4);
      uint2 o;
      o.x = pack2(v.x, v.y);
      o.y = pack2(v.z, v.w);
      *(uint2*)(arena + e4) = o;
    } else {
      *(uint2*)(arena + e4) = *(const uint2*)(sp + (size_t)rel * 2);
    }
  } else {
#pragma unroll
    for (int k = 0; k < 4; ++k) {
      u16 o = 0;
      if (rel + k < cnt)
        o = f32 ? f2b(((const float*)sp)[rel + k]) : ((const u16*)sp)[rel + k];
      arena[e4 + k] = o;
    }
  }
}

// ---------------- bias concat: bqkv=[bq|bk|bv], bkv=[bk|bv] ----------------
__global__ void biascat_kernel(const u16* __restrict__ bq, const u16* __restrict__ bk,
                               const u16* __restrict__ bv, u16* __restrict__ bqkv,
                               u16* __restrict__ bkv) {
  int t = threadIdx.x;  // 512
  bqkv[t] = bq[t];
  bqkv[512 + t] = bk[t];
  bqkv[1024 + t] = bv[t];
  bkv[t] = bk[t];
  bkv[512 + t] = bv[t];
}

// ---------------- GEMM: m97 pattern + XCD swizzle + coalesced epilogue + 2-PHASE PIPELINE --
template <int ACT>
__global__ __launch_bounds__(256, 4) void gemm_bt(
    const u16* __restrict__ A, const u16* __restrict__ Bt,
    const u16* __restrict__ bias, u16* __restrict__ Co, int Mtot, int Ntot, int nby) {
  __shared__ __align__(16) u16 smem[128 * 136];  // staging dbuf (32KB) / epilogue st (34.8KB)
  u16* const aB0 = smem;
  u16* const aB1 = smem + 4096;
  u16* const bB0 = smem + 8192;
  u16* const bB1 = smem + 12288;
  const int tid = threadIdx.x;
  const int lane = tid & 63;
  const int w = tid >> 6;
  const int quad = lane >> 4;
  const int l15 = lane & 15;

  const int nwg = gridDim.x;
  const int orig = blockIdx.x;
  const int xcd = orig & 7, sq = orig >> 3;
  const int qd = nwg >> 3, rm = nwg & 7;
  const int wg = (xcd < rm ? xcd * (qd + 1) : rm * (qd + 1) + (xcd - rm) * qd) + sq;
  const int m0 = (wg / nby) * 128;
  const int n0 = (wg % nby) * 128;

  const int wm = (w & 1) << 6;
  const int wn = (w >> 1) << 6;

  f32x4 acc[4][4] = {};

  const u16* ga[2];
  const u16* gb[2];
#pragma unroll
  for (int q = 0; q < 2; ++q) {
    int j = q * 256 + tid;
    int r = j >> 2, s = j & 3;
    int c = (s ^ ((r >> 1) & 3)) * 8;
    int ra = m0 + r;
    if (ra >= Mtot) ra = Mtot - 1;
    ga[q] = A + (size_t)ra * 512 + c;
    gb[q] = Bt + (size_t)(n0 + r) * 512 + c;
  }

  auto stage = [&](int p, int ko) {
    u16* ab = p ? aB1 : aB0;
    u16* bb = p ? bB1 : bB0;
#pragma unroll
    for (int q = 0; q < 2; ++q) {
      int j = q * 256 + tid;
      gll16(ga[q] + ko * 32, ab + j * 8);
      gll16(gb[q] + ko * 32, bb + j * 8);
    }
  };

  stage(0, 0);
  __syncthreads();
  int cur = 0;
  for (int ko = 0; ko < 16; ++ko) {
    if (ko < 15) stage(cur ^ 1, ko + 1);
    u16* ab = cur ? aB1 : aB0;
    u16* bb = cur ? bB1 : bB0;
    bf16x8 af[4], bfr[4];
#pragma unroll
    for (int i = 0; i < 4; ++i) {
      int r = wm + i * 16 + l15;
      af[i] = *(const bf16x8*)(ab + (((r << 2) | (quad ^ ((r >> 1) & 3)))) * 8);
      int rn = wn + i * 16 + l15;
      bfr[i] = *(const bf16x8*)(bb + (((rn << 2) | (quad ^ ((rn >> 1) & 3)))) * 8);
    }
#pragma unroll
    for (int i = 0; i < 4; ++i)
#pragma unroll
      for (int jn = 0; jn < 4; ++jn)
        acc[i][jn] = MFMA16(af[i], bfr[jn], acc[i][jn]);
    __syncthreads();
    cur ^= 1;
  }

  // epilogue: bias/act -> bf16 into LDS st[128][136], then coalesced 16B stores
  u16* st = smem;
  const int cl = l15;
  const int rg = quad;
#pragma unroll
  for (int jn = 0; jn < 4; ++jn) {
    int coll = wn + jn * 16 + cl;
    float bv = b2f(bias[n0 + coll]);
#pragma unroll
    for (int i = 0; i < 4; ++i) {
      int rowb = wm + i * 16 + rg * 4;
#pragma unroll
      for (int rr = 0; rr < 4; ++rr) {
        float vv = acc[i][jn][rr] + bv;
        if (ACT) vv = fmaxf(vv, 0.f);
        st[(rowb + rr) * 136 + coll] = f2b(vv);
      }
    }
  }
  __syncthreads();
#pragma unroll
  for (int t = 0; t < 8; ++t) {
    int idx = (t * 256 + tid) * 8;  // u16 units within 128x128 tile
    int r = idx >> 7;
    int c = idx & 127;
    int row = m0 + r;
    if (row < Mtot) {
      uint4 v = *(const uint4*)(st + r * 136 + c);
      *(uint4*)(Co + (size_t)row * Ntot + n0 + c) = v;
    }
  }
}

// ---------------- fused MLP(2 layers, shared Wm) + residual + LayerNorm, in-place -------
// Block = 64 full rows (BN=512). Phase 1: h1 = relu(mem@Wm+bm) -> LDS (64x512 bf16,
// chunk-XOR swizzled). Phase 2: h2 = relu(h1@Wm+bm) reading h1 straight from LDS (no
// staging, no barriers in the K-loop); B-fragments for both phases stream from L2-hot WmT.
// Epilogue: x = bf16(h2) + mem (residual), in-block LN over the full 512-wide rows
// (cross-wave reduce via LDS), coalesced in-place write. Replaces 2 GEMM dispatches + ln2
// and their qbuf/obuf round-trips (~170MB/iter).
__global__ __launch_bounds__(256, 2) void gemm_mlp_ln(
    u16* __restrict__ mem, const u16* __restrict__ WmT, const u16* __restrict__ bm,
    const u16* __restrict__ g2, const u16* __restrict__ b2) {
  __shared__ __align__(16) u16 h1[64 * 512];     // 64KB
  __shared__ __align__(16) u16 ast[2][64 * 32];  // A staging dbuf 8KB
  __shared__ float red[4][64][2];                // per-wave row partials (sum, sumsq)
  const int tid = threadIdx.x;
  const int lane = tid & 63;
  const int w = tid >> 6;
  const int quad = lane >> 4;
  const int l15 = lane & 15;
  const int m0 = blockIdx.x * 64;   // 645 * 64 = 41280 exact
  const int nw = w * 128;           // wave col strip

  const int sr = tid >> 2, ss = tid & 3;
  const u16* ga = mem + (size_t)(m0 + sr) * 512 + ((ss ^ ((sr >> 1) & 3)) * 8);

  f32x4 acc[4][8] = {};

  // ---- phase 1: h1 = relu(mem @ Wm + bm) ----
  gll16(ga, &ast[0][0] + tid * 8);
  __syncthreads();
  for (int ko = 0; ko < 16; ++ko) {
    if (ko < 15) gll16(ga + (ko + 1) * 32, &ast[(ko + 1) & 1][0] + tid * 8);
    const u16* ab = &ast[ko & 1][0];
    bf16x8 af[4];
#pragma unroll
    for (int i = 0; i < 4; ++i) {
      int r = i * 16 + l15;
      af[i] = *(const bf16x8*)(ab + (((r << 2) | (quad ^ ((r >> 1) & 3)))) * 8);
    }
#pragma unroll
    for (int j = 0; j < 8; ++j) {
      int col = nw + j * 16 + l15;
      bf16x8 bfr = *(const bf16x8*)(WmT + (size_t)col * 512 + ko * 32 + quad * 8);
#pragma unroll
      for (int i = 0; i < 4; ++i) acc[i][j] = MFMA16(af[i], bfr, acc[i][j]);
    }
    __syncthreads();
  }

  // h1 -> LDS, chunk-of-8 XOR swizzle per row (read-side 2-way banks)
#pragma unroll
  for (int j = 0; j < 8; ++j) {
    int col = nw + j * 16 + l15;
    float bv = b2f(bm[col]);
    int chunk = col >> 3, cin = col & 7;
#pragma unroll
    for (int i = 0; i < 4; ++i)
#pragma unroll
      for (int rr = 0; rr < 4; ++rr) {
        int row = i * 16 + quad * 4 + rr;
        h1[row * 512 + ((chunk ^ (row & 7)) << 3) + cin] =
            f2b(fmaxf(acc[i][j][rr] + bv, 0.f));
      }
  }
  __syncthreads();

  // ---- phase 2: h2 = relu(h1 @ Wm + bm), A straight from LDS, no barriers ----
#pragma unroll
  for (int i = 0; i < 4; ++i)
#pragma unroll
    for (int j = 0; j < 8; ++j) acc[i][j] = (f32x4){0.f, 0.f, 0.f, 0.f};
  for (int ko = 0; ko < 16; ++ko) {
    bf16x8 af[4];
#pragma unroll
    for (int i = 0; i < 4; ++i) {
      int r = i * 16 + l15;
      af[i] = *(const bf16x8*)(h1 + r * 512 + ((((ko << 2) + quad) ^ (r & 7)) << 3));
    }
#pragma unroll
    for (int j = 0; j < 8; ++j) {
      int col = nw + j * 16 + l15;
      bf16x8 bfr = *(const bf16x8*)(WmT + (size_t)col * 512 + ko * 32 + quad * 8);
#pragma unroll
      for (int i = 0; i < 4; ++i) acc[i][j] = MFMA16(af[i], bfr, acc[i][j]);
    }
  }

  // ---- epilogue: x = bf16(h2) + residual, LN stats (partial) ----
  float ps[4][4], pq[4][4];
#pragma unroll
  for (int i = 0; i < 4; ++i)
#pragma unroll
    for (int rr = 0; rr < 4; ++rr) { ps[i][rr] = 0.f; pq[i][rr] = 0.f; }
#pragma unroll
  for (int j = 0; j < 8; ++j) {
    int col = nw + j * 16 + l15;
    float bv = b2f(bm[col]);
#pragma unroll
    for (int i = 0; i < 4; ++i)
#pragma unroll
      for (int rr = 0; rr < 4; ++rr) {
        int row = i * 16 + quad * 4 + rr;
        float h2 = fmaxf(acc[i][j][rr] + bv, 0.f);
        float x = b2f(f2b(h2)) + b2f(mem[(size_t)(m0 + row) * 512 + col]);
        acc[i][j][rr] = x;
        ps[i][rr] += x;
        pq[i][rr] = fmaf(x, x, pq[i][rr]);
      }
  }
  // reduce across the 16 l15-lanes (stays within the quad's 16-lane group)
#pragma unroll
  for (int off = 1; off < 16; off <<= 1)
#pragma unroll
    for (int i = 0; i < 4; ++i)
#pragma unroll
      for (int rr = 0; rr < 4; ++rr) {
        ps[i][rr] += __shfl_xor(ps[i][rr], off, 64);
        pq[i][rr] += __shfl_xor(pq[i][rr], off, 64);
      }
  if (l15 == 0) {
#pragma unroll
    for (int i = 0; i < 4; ++i)
#pragma unroll
      for (int rr = 0; rr < 4; ++rr) {
        int row = i * 16 + quad * 4 + rr;
        red[w][row][0] = ps[i][rr];
        red[w][row][1] = pq[i][rr];
      }
  }
  __syncthreads();  // also: all h1 reads complete past this point

  // final stats + normalize + stage to h1 (linear) for coalesced store
#pragma unroll
  for (int i = 0; i < 4; ++i)
#pragma unroll
    for (int rr = 0; rr < 4; ++rr) {
      int row = i * 16 + quad * 4 + rr;
      float s = red[0][row][0] + red[1][row][0] + red[2][row][0] + red[3][row][0];
      float q = red[0][row][1] + red[1][row][1] + red[2][row][1] + red[3][row][1];
      float mu = s * (1.f / 512.f);
      float var = fmaxf(q * (1.f / 512.f) - mu * mu, 0.f);
      float rstd = rsqrtf(var + 1e-5f);
#pragma unroll
      for (int j = 0; j < 8; ++j) {
        int col = nw + j * 16 + l15;
        h1[row * 512 + col] =
            f2b(fmaf((acc[i][j][rr] - mu) * rstd, b2f(g2[col]), b2f(b2[col])));
      }
    }
  __syncthreads();
#pragma unroll
  for (int t = 0; t < 16; ++t) {
    int idx = (t * 256 + tid) * 8;
    int row = idx >> 9, col = idx & 511;
    *(uint4*)(mem + (size_t)(m0 + row) * 512 + col) = *(const uint4*)(h1 + row * 512 + col);
  }
}

// ---------------- gate GEMM + gates fused (2-phase pipelined) ----------------
__global__ __launch_bounds__(256, 4) void gemm_gates(
    const u16* __restrict__ A, const u16* __restrict__ WmgTp,
    const u16* __restrict__ bmg, const u16* __restrict__ gi,
    const u16* __restrict__ memfin, const u16* __restrict__ mem_in,
    const u16* __restrict__ ibp, const u16* __restrict__ fbp,
    u16* __restrict__ nmbf, void* __restrict__ outp, const int* __restrict__ flag,
    int Mtot) {
  __shared__ __align__(16) u16 smem[128 * 136];
  u16* const aB0 = smem;
  u16* const aB1 = smem + 4096;
  u16* const bB0 = smem + 8192;
  u16* const bB1 = smem + 12288;
  const int tid = threadIdx.x;
  const int lane = tid & 63;
  const int w = tid >> 6;
  const int quad = lane >> 4;
  const int l15 = lane & 15;

  const int nwg = gridDim.x;
  const int orig = blockIdx.x;
  const int xcd = orig & 7, sq = orig >> 3;
  const int qd = nwg >> 3, rm = nwg & 7;
  const int wg = (xcd < rm ? xcd * (qd + 1) : rm * (qd + 1) + (xcd - rm) * qd) + sq;
  const int m0 = (wg >> 3) * 128;    // nby = 8
  const int n0h = (wg & 7) * 64;     // col offset within [0,512)

  const int wm = (w & 1) << 6;
  const int wn = (w >> 1) << 6;

  f32x4 acc[4][4] = {};

  const u16* ga[2];
  const u16* gb[2];
#pragma unroll
  for (int q = 0; q < 2; ++q) {
    int j = q * 256 + tid;
    int r = j >> 2, s = j & 3;
    int c = (s ^ ((r >> 1) & 3)) * 8;
    int ra = m0 + r;
    if (ra >= Mtot) ra = Mtot - 1;
    ga[q] = A + (size_t)ra * 512 + c;
    int br = (r < 64) ? (n0h + r) : (512 + n0h + r - 64);  // ig half | fg half
    gb[q] = WmgTp + (size_t)br * 512 + c;
  }

  auto stage = [&](int p, int ko) {
    u16* ab = p ? aB1 : aB0;
    u16* bb = p ? bB1 : bB0;
#pragma unroll
    for (int q = 0; q < 2; ++q) {
      int j = q * 256 + tid;
      gll16(ga[q] + ko * 32, ab + j * 8);
      gll16(gb[q] + ko * 32, bb + j * 8);
    }
  };

  stage(0, 0);
  __syncthreads();
  int cur = 0;
  for (int ko = 0; ko < 16; ++ko) {
    if (ko < 15) stage(cur ^ 1, ko + 1);
    u16* ab = cur ? aB1 : aB0;
    u16* bb = cur ? bB1 : bB0;
    bf16x8 af[4], bfr[4];
#pragma unroll
    for (int i = 0; i < 4; ++i) {
      int r = wm + i * 16 + l15;
      af[i] = *(const bf16x8*)(ab + (((r << 2) | (quad ^ ((r >> 1) & 3)))) * 8);
      int rn = wn + i * 16 + l15;
      bfr[i] = *(const bf16x8*)(bb + (((rn << 2) | (quad ^ ((rn >> 1) & 3)))) * 8);
    }
#pragma unroll
    for (int i = 0; i < 4; ++i)
#pragma unroll
      for (int jn = 0; jn < 4; ++jn)
        acc[i][jn] = MFMA16(af[i], bfr[jn], acc[i][jn]);
    __syncthreads();
    cur ^= 1;
  }

  // stage gm (bf16, with bmg bias) into LDS: cols 0..63 = ig, 64..127 = fg
  u16* st = smem;
#pragma unroll
  for (int jn = 0; jn < 4; ++jn) {
    int coll = wn + jn * 16 + l15;
    int bcol = (coll < 64) ? (n0h + coll) : (512 + n0h + coll - 64);
    float bv = b2f(bmg[bcol]);
#pragma unroll
    for (int i = 0; i < 4; ++i) {
      int rowb = wm + i * 16 + quad * 4;
#pragma unroll
      for (int rr = 0; rr < 4; ++rr)
        st[(rowb + rr) * 136 + coll] = f2b(acc[i][jn][rr] + bv);
    }
  }
  __syncthreads();

  const float ib = b2f(ibp[0]);
  const float fb = b2f(fbp[0]);
  const bool of32 = (*flag != 0);
#pragma unroll
  for (int t = 0; t < 4; ++t) {
    int chunk = t * 256 + tid;        // 1024 chunks of 8 elems = 128 rows x 64 cols
    int rl = chunk >> 3;
    int c8 = (chunk & 7) * 8;
    int row = m0 + rl;
    if (row >= Mtot) continue;
    int b = row / 1290;
    size_t gidx = (size_t)row * 512 + n0h + c8;
    uint4 uig = *(const uint4*)(st + rl * 136 + c8);
    uint4 ufg = *(const uint4*)(st + rl * 136 + 64 + c8);
    uint4 ugi = *(const uint4*)(gi + b * 1024 + n0h + c8);
    uint4 ugf = *(const uint4*)(gi + b * 1024 + 512 + n0h + c8);
    uint4 umf = *(const uint4*)(memfin + gidx);
    uint4 umi = *(const uint4*)(mem_in + gidx);
    const u32* pig = (const u32*)&uig;
    const u32* pfg = (const u32*)&ufg;
    const u32* pgi = (const u32*)&ugi;
    const u32* pgf = (const u32*)&ugf;
    const u32* pmf = (const u32*)&umf;
    const u32* pmi = (const u32*)&umi;
    float v[8];
#pragma unroll
    for (int k = 0; k < 4; ++k) {
      float ig0 = sigm(blo(pig[k]) + blo(pgi[k]) + ib);
      float ig1 = sigm(bhi(pig[k]) + bhi(pgi[k]) + ib);
      float fg0 = sigm(blo(pfg[k]) + blo(pgf[k]) + fb);
      float fg1 = sigm(bhi(pfg[k]) + bhi(pgf[k]) + fb);
      v[2 * k] = ig0 * ftanh(blo(pmf[k])) + fg0 * blo(pmi[k]);
      v[2 * k + 1] = ig1 * ftanh(bhi(pmf[k])) + fg1 * bhi(pmi[k]);
    }
    uint4 o;
    u32* po = (u32*)&o;
#pragma unroll
    for (int k = 0; k < 4; ++k) po[k] = pack2(v[2 * k], v[2 * k + 1]);
    *(uint4*)(nmbf + gidx) = o;
    if (of32) {
      float4 f0, f1;
      f0.x = v[0]; f0.y = v[1]; f0.z = v[2]; f0.w = v[3];
      f1.x = v[4]; f1.y = v[5]; f1.z = v[6]; f1.w = v[7];
      *(float4*)((float*)outp + gidx) = f0;
      *(float4*)((float*)outp + gidx + 4) = f1;
    } else {
      *(uint4*)((u16*)outp + gidx) = o;
    }
  }
}

// ---------------- weight transpose ----------------
__global__ __launch_bounds__(256) void transpose_kernel(const u16* __restrict__ in,
                                                        u16* __restrict__ outb, int K, int N) {
  __shared__ u16 tile[32][33];
  const int tx = threadIdx.x & 31, ty = threadIdx.x >> 5;
  const int bx = blockIdx.x * 32;
  const int by = blockIdx.y * 32;
#pragma unroll
  for (int i = 0; i < 32; i += 8) tile[ty + i][tx] = in[(size_t)(by + ty + i) * N + bx + tx];
  __syncthreads();
#pragma unroll
  for (int i = 0; i < 32; i += 8) outb[(size_t)(bx + ty + i) * K + by + tx] = tile[tx][ty + i];
}

// ---------------- tanh(memory) ----------------
__global__ void tanhmem_kernel(const u16* __restrict__ mi, u16* __restrict__ th, int n8) {
  int i = blockIdx.x * 256 + threadIdx.x;
  if (i >= n8) return;
  uint4 u = ((const uint4*)mi)[i];
  uint4 t;
  t.x = pack2(ftanh(blo(u.x)), ftanh(bhi(u.x)));
  t.y = pack2(ftanh(blo(u.y)), ftanh(bhi(u.y)));
  t.z = pack2(ftanh(blo(u.z)), ftanh(bhi(u.z)));
  t.w = pack2(ftanh(blo(u.w)), ftanh(bhi(u.w)));
  ((uint4*)th)[i] = t;
}

// ---------------- rmean ----------------
__global__ void redmean_kernel(const u16* __restrict__ inp, const u16* __restrict__ repw,
                               u16* __restrict__ outb) {
  const int b = blockIdx.x;
  const int c = blockIdx.y * 256 + threadIdx.x;
  const float rw = b2f(repw[c]);
  float s = 0.f;
  for (int t = 0; t < 128; ++t)
    s += fmaxf(rw * b2f(inp[(size_t)(b * 128 + t) * 512 + c]), 0.f);
  outb[b * 512 + c] = f2b(s * (1.f / 128.f));
}

// ---------------- LayerNorm (4 rows/block, 1 wave per row) ----------------
__global__ __launch_bounds__(256) void ln_kernel(const u16* __restrict__ src,
                                                 const u16* __restrict__ addb,
                                                 u16* __restrict__ dst,
                                                 const u16* __restrict__ g,
                                                 const u16* __restrict__ bb) {
  const int row = blockIdx.x * 4 + (threadIdx.x >> 6);
  const int lane = threadIdx.x & 63;
  const u16* srow = src + (size_t)row * 512;
  const u16* arow = addb + (size_t)row * 512;
  float x[8];
  float s = 0.f;
#pragma unroll
  for (int i = 0; i < 8; ++i) {
    int c = lane + i * 64;
    x[i] = b2f(srow[c]) + b2f(arow[c]);
    s += x[i];
  }
#pragma unroll
  for (int off = 32; off > 0; off >>= 1) s += __shfl_xor(s, off, 64);
  const float mu = s * (1.f / 512.f);
  float v = 0.f;
#pragma unroll
  for (int i = 0; i < 8; ++i) {
    float d = x[i] - mu;
    v = fmaf(d, d, v);
  }
#pragma unroll
  for (int off = 32; off > 0; off >>= 1) v += __shfl_xor(v, off, 64);
  const float rstd = rsqrtf(v * (1.f / 512.f) + 1e-5f);
  u16* orow = dst + (size_t)row * 512;
#pragma unroll
  for (int i = 0; i < 8; ++i) {
    int c = lane + i * 64;
    orow[c] = f2b(fmaf((x[i] - mu) * rstd, b2f(g[c]), b2f(bb[c])));
  }
}

// ---------------- attention 1 (MFMA): 1290 q (mem), 128 k (inp), top-8 mask ----------------
__global__ __launch_bounds__(256, 3) void attn1_mfma(const u16* __restrict__ q,
                                                     const u16* __restrict__ kb,
                                                     const u16* __restrict__ vb,
                                                     u16* __restrict__ o, int ldkv) {
  __shared__ __align__(16) u16 Pl[128 * 136];  // masked P [q][k]; rows 0..60 alias Kl
  __shared__ __align__(16) u16 VT[64 * 136];   // V^T [d][k]
  __shared__ float lbuf[128];                  // 1/l per local query
  u16* Kl = Pl;                                // phase-1 alias: swizzled K [key][dim]

  const int tid = threadIdx.x;
  const int lane = tid & 63;
  const int w = tid >> 6;
  const int quad = lane >> 4;
  const int l15 = lane & 15;
  const int qb = blockIdx.x;
  const int bh = blockIdx.y;
  const int b = bh >> 3, h = bh & 7;

  // stage K swizzled (gll16) into Kl
#pragma unroll
  for (int qq = 0; qq < 4; ++qq) {
    int j = qq * 256 + tid;
    int r = j >> 3, s = j & 7;
    gll16(kb + (size_t)(b * 128 + r) * ldkv + h * 64 + (s ^ (r & 7)) * 8, Kl + j * 8);
  }
  // stage V transposed: per wave, 64 consecutive keys per d-row write (2-way banks, free)
#pragma unroll
  for (int p = 0; p < 4; ++p) {
    int key = (tid & 63) + 64 * (p & 1);
    int dc = w + 4 * (p >> 1);
    uint4 u = *(const uint4*)(vb + (size_t)(b * 128 + key) * ldkv + h * 64 + dc * 8);
    u16 tmp[8];
    *(uint4*)tmp = u;
#pragma unroll
    for (int jj = 0; jj < 8; ++jj) VT[(dc * 8 + jj) * 136 + key] = tmp[jj];
  }

  // Q fragments (B-operand): col = query, quad picks dim-chunk
  bf16x8 bq[2][2];
  {
    int ra = min(qb * 128 + w * 32 + l15, 1289);
    int rb_ = min(qb * 128 + w * 32 + 16 + l15, 1289);
    const u16* qa = q + (size_t)(b * 1290 + ra) * 512 + h * 64 + quad * 8;
    const u16* qc = q + (size_t)(b * 1290 + rb_) * 512 + h * 64 + quad * 8;
    bq[0][0] = *(const bf16x8*)(qa);
    bq[0][1] = *(const bf16x8*)(qa + 32);
    bq[1][0] = *(const bf16x8*)(qc);
    bq[1][1] = *(const bf16x8*)(qc + 32);
  }
  __syncthreads();

  // S^T = K.Q^T : thread holds query (w*32+i*16+l15), k = jn*16+quad*4+rr
  f32x4 sa[2][8] = {};
#pragma unroll
  for (int ks = 0; ks < 2; ++ks) {
#pragma unroll
    for (int jn = 0; jn < 8; ++jn) {
      int n = jn * 16 + l15;
      int cch = ks * 4 + quad;
      bf16x8 ak = *(const bf16x8*)(Kl + (n * 8 + (cch ^ (n & 7))) * 8);
      sa[0][jn] = MFMA16(ak, bq[0][ks], sa[0][jn]);
      sa[1][jn] = MFMA16(ak, bq[1][ks], sa[1][jn]);
    }
  }
  __syncthreads();  // all Kl reads done before P overwrites the aliased region

  const u32 ibase = 127u - (u32)(quad * 4);
#pragma unroll
  for (int i = 0; i < 2; ++i) {
    const int qi = w * 32 + i * 16 + l15;
    // build packed keys (scale scores in place; sa keeps f32 for the exp pass)
    u32 g[4][8];
#pragma unroll
    for (int jn = 0; jn < 8; ++jn)
#pragma unroll
      for (int rr = 0; rr < 4; ++rr) {
        float s = sa[i][jn][rr] * 0.125f;
        sa[i][jn][rr] = s;
        g[jn >> 1][(jn & 1) * 4 + rr] =
            (fmono(s) & 0xFFFFFF80u) | (ibase - (u32)(jn * 16 + rr));
      }
    // local top-8: 4x sort8 + merge tree
    sort8_desc(g[0]); sort8_desc(g[1]); sort8_desc(g[2]); sort8_desc(g[3]);
    merge_top8(g[0], g[1]);
    merge_top8(g[2], g[3]);
    merge_top8(g[0], g[2]);
    u32* tv = g[0];
    // merge sorted top-8 lists across quads (xor 16, then 32)
#pragma unroll
    for (int off = 16; off < 64; off <<= 1) {
      u32 pv[8];
#pragma unroll
      for (int j = 0; j < 8; ++j) pv[j] = (u32)__shfl_xor((int)tv[7 - j], off, 64);
#pragma unroll
      for (int j = 0; j < 8; ++j) tv[j] = max(tv[j], pv[j]);
      bitonic8_desc(tv);
    }
    const u32 t8 = tv[7];  // 8th largest packed key; membership = (key >= t8)
    // decode running max (25-bit truncated; <= true max, safe for exp)
    u32 mb = tv[0] & 0xFFFFFF80u;
    u32 xm = (mb & 0x80000000u) ? (mb ^ 0x80000000u) : ~mb;
    const float mx = __uint_as_float(xm);
    // single pass: denom over all 128 + masked unnormalized P write
    float lsum = 0.f;
#pragma unroll
    for (int jn = 0; jn < 8; ++jn) {
      u16 pr[4];
#pragma unroll
      for (int rr = 0; rr < 4; ++rr) {
        float s = sa[i][jn][rr];
        float e = __expf(s - mx);
        lsum += e;
        u32 kk = (fmono(s) & 0xFFFFFF80u) | (ibase - (u32)(jn * 16 + rr));
        pr[rr] = (kk >= t8) ? f2b(e) : (u16)0;
      }
      uint2 st;
      st.x = (u32)pr[0] | ((u32)pr[1] << 16);
      st.y = (u32)pr[2] | ((u32)pr[3] << 16);
      *(uint2*)(Pl + qi * 136 + jn * 16 + quad * 4) = st;
    }
    lsum += __shfl_xor(lsum, 16, 64);
    lsum += __shfl_xor(lsum, 32, 64);
    if (quad == 0) lbuf[qi] = 1.f / lsum;
  }
  __syncthreads();

  // O = P.V  (A = masked P rows, B = VT rows)
  f32x4 oa[2][4] = {};
#pragma unroll
  for (int kc = 0; kc < 4; ++kc) {
    bf16x8 ap[2];
#pragma unroll
    for (int i = 0; i < 2; ++i)
      ap[i] = *(const bf16x8*)(Pl + (w * 32 + i * 16 + l15) * 136 + kc * 32 + quad * 8);
#pragma unroll
    for (int jd = 0; jd < 4; ++jd) {
      bf16x8 bv_ = *(const bf16x8*)(VT + (jd * 16 + l15) * 136 + kc * 32 + quad * 8);
      oa[0][jd] = MFMA16(ap[0], bv_, oa[0][jd]);
      oa[1][jd] = MFMA16(ap[1], bv_, oa[1][jd]);
    }
  }

  // epilogue: scale rows by 1/l, write bf16
#pragma unroll
  for (int i = 0; i < 2; ++i) {
    int rowl = w * 32 + i * 16 + quad * 4;
#pragma unroll
    for (int rr = 0; rr < 4; ++rr) {
      int qg = qb * 128 + rowl + rr;
      if (qg < 1290) {
        float il = lbuf[rowl + rr];
        u16* orow = o + (size_t)(b * 1290 + qg) * 512 + h * 64;
#pragma unroll
        for (int jd = 0; jd < 4; ++jd) orow[jd * 16 + l15] = f2b(oa[i][jd][rr] * il);
      }
    }
  }
}

// ---------------- attention 2 (MFMA flash): 128 q (inp), 1290 k (next_memory) ----------------
__global__ __launch_bounds__(256, 2) void attn2_mfma(const u16* __restrict__ q2,
                                                     const u16* __restrict__ k2,
                                                     const u16* __restrict__ v2,
                                                     float* __restrict__ pacc,
                                                     float* __restrict__ pml,
                                                     int ldq, int ldkv) {
  __shared__ __align__(16) u16 Kl[64 * 64];      // swizzled [key][dim]
  __shared__ __align__(16) u16 VT[64 * 72];      // [dim][key], stride 72
  __shared__ __align__(16) u16 Pl[4 * 32 * 72];  // per-wave P [32q][64k]
  const int tid = threadIdx.x;
  const int lane = tid & 63;
  const int w = tid >> 6;
  const int quad = lane >> 4;
  const int l15 = lane & 15;
  const int bh = blockIdx.x;
  const int b = bh >> 3, h = bh & 7;
  const int part = blockIdx.y;
  const int kstart = (part * 1290) >> 2;
  const int kend = ((part + 1) * 1290) >> 2;

  bf16x8 aq[2][2];
  {
    int r0 = b * 128 + w * 32 + l15;
    const u16* qa = q2 + (size_t)r0 * ldq + h * 64 + quad * 8;
    aq[0][0] = *(const bf16x8*)(qa);
    aq[0][1] = *(const bf16x8*)(qa + 32);
    aq[1][0] = *(const bf16x8*)(qa + (size_t)16 * ldq);
    aq[1][1] = *(const bf16x8*)(qa + (size_t)16 * ldq + 32);
  }

  f32x4 oa[2][4] = {};
  float m_[2][4], l_[2][4];
#pragma unroll
  for (int i = 0; i < 2; ++i)
#pragma unroll
    for (int r = 0; r < 4; ++r) { m_[i][r] = -1e30f; l_[i][r] = 0.f; }

  const int nk = kend - kstart;
  for (int kt = 0; kt < nk; kt += 64) {
    __syncthreads();
    // stage K swizzled (gll16)
#pragma unroll
    for (int qq = 0; qq < 2; ++qq) {
      int j = qq * 256 + tid;
      int r = j >> 3, s = j & 7;
      int kg = kstart + kt + r;
      if (kg >= kend) kg = kend - 1;
      gll16(k2 + (size_t)(b * 1290 + kg) * ldkv + h * 64 + (s ^ (r & 7)) * 8, Kl + j * 8);
    }
    // stage V transposed: lane r = key, dc = dim chunk (write banks: const + r/2 -> 2-way free)
    {
      int r = tid & 63;
      int kg = kstart + kt + r;
      if (kg >= kend) kg = kend - 1;
      const u16* vrow = v2 + (size_t)(b * 1290 + kg) * ldkv + h * 64;
#pragma unroll
      for (int p = 0; p < 2; ++p) {
        int dc = (tid >> 6) + p * 4;
        uint4 u = *(const uint4*)(vrow + dc * 8);
        u16 tmp[8];
        *(uint4*)tmp = u;
#pragma unroll
        for (int jj = 0; jj < 8; ++jj) VT[(dc * 8 + jj) * 72 + r] = tmp[jj];
      }
    }
    __syncthreads();

    // S = Q.K^T
    f32x4 sa[2][4] = {};
#pragma unroll
    for (int ks = 0; ks < 2; ++ks) {
#pragma unroll
      for (int jn = 0; jn < 4; ++jn) {
        int n = jn * 16 + l15;
        int cch = ks * 4 + quad;
        bf16x8 bk = *(const bf16x8*)(Kl + (n * 8 + (cch ^ (n & 7))) * 8);
        sa[0][jn] = MFMA16(aq[0][ks], bk, sa[0][jn]);
        sa[1][jn] = MFMA16(aq[1][ks], bk, sa[1][jn]);
      }
    }

    // online softmax (C-layout: col=l15 is key, row=quad*4+r is query) + P to LDS
    u16* pw = Pl + w * (32 * 72);
#pragma unroll
    for (int i = 0; i < 2; ++i) {
      float rmax[4] = {-1e30f, -1e30f, -1e30f, -1e30f};
#pragma unroll
      for (int jn = 0; jn < 4; ++jn) {
        int kg = kstart + kt + jn * 16 + l15;
        bool val = kg < kend;
#pragma unroll
        for (int r = 0; r < 4; ++r) {
          float s = sa[i][jn][r] * 0.125f;
          s = val ? s : -1e30f;
          sa[i][jn][r] = s;
          rmax[r] = fmaxf(rmax[r], s);
        }
      }
#pragma unroll
      for (int off = 1; off < 16; off <<= 1)
#pragma unroll
        for (int r = 0; r < 4; ++r) rmax[r] = fmaxf(rmax[r], __shfl_xor(rmax[r], off, 64));
      float alpha[4];
#pragma unroll
      for (int r = 0; r < 4; ++r) {
        float mn = fmaxf(m_[i][r], rmax[r]);
        alpha[r] = __expf(m_[i][r] - mn);
        m_[i][r] = mn;
      }
      float lsum[4] = {0.f, 0.f, 0.f, 0.f};
#pragma unroll
      for (int jn = 0; jn < 4; ++jn)
#pragma unroll
        for (int r = 0; r < 4; ++r) {
          float p = __expf(sa[i][jn][r] - m_[i][r]);
          sa[i][jn][r] = p;
          lsum[r] += p;
        }
#pragma unroll
      for (int off = 1; off < 16; off <<= 1)
#pragma unroll
        for (int r = 0; r < 4; ++r) lsum[r] += __shfl_xor(lsum[r], off, 64);
#pragma unroll
      for (int r = 0; r < 4; ++r) l_[i][r] = l_[i][r] * alpha[r] + lsum[r];
#pragma unroll
      for (int jd = 0; jd < 4; ++jd)
#pragma unroll
        for (int r = 0; r < 4; ++r) oa[i][jd][r] *= alpha[r];
#pragma unroll
      for (int jn = 0; jn < 4; ++jn) {
        int col = jn * 16 + l15;
#pragma unroll
        for (int r = 0; r < 4; ++r)
          pw[(i * 16 + quad * 4 + r) * 72 + col] = f2b(sa[i][jn][r]);
      }
    }

    // O += P.V   (A = P from per-wave LDS, B = VT)
#pragma unroll
    for (int ks = 0; ks < 2; ++ks) {
      bf16x8 ap[2];
#pragma unroll
      for (int i = 0; i < 2; ++i)
        ap[i] = *(const bf16x8*)(pw + (i * 16 + l15) * 72 + ks * 32 + quad * 8);
#pragma unroll
      for (int jd = 0; jd < 4; ++jd) {
        bf16x8 bv_ = *(const bf16x8*)(VT + (jd * 16 + l15) * 72 + ks * 32 + quad * 8);
        oa[0][jd] = MFMA16(ap[0], bv_, oa[0][jd]);
        oa[1][jd] = MFMA16(ap[1], bv_, oa[1][jd]);
      }
    }
  }

  // store partials (C-layout scatter)
  float* pa = pacc + (size_t)(part * 256 + bh) * 128 * 64;
#pragma unroll
  for (int i = 0; i < 2; ++i) {
    int row = w * 32 + i * 16 + quad * 4;
#pragma unroll
    for (int r = 0; r < 4; ++r)
#pragma unroll
      for (int jd = 0; jd < 4; ++jd)
        pa[(size_t)(row + r) * 64 + jd * 16 + l15] = oa[i][jd][r];
    if (l15 == 0) {
#pragma unroll
      for (int r = 0; r < 4; ++r) {
        size_t pi = (size_t)(part * 256 + bh) * 128 + row + r;
        pml[pi * 2 + 0] = m_[i][r];
        pml[pi * 2 + 1] = l_[i][r];
      }
    }
  }
}

__global__ __launch_bounds__(64) void attn2_merge(const float* __restrict__ pacc,
                                                  const float* __restrict__ pml,
                                                  void* __restrict__ outp,
                                                  const int* __restrict__ flag) {
  const int qi = blockIdx.x;  // bh*128 + t
  const int bh = qi >> 7, t = qi & 127;
  const int b = bh >> 3, h = bh & 7;
  const int lane = threadIdx.x;
  float mv[4], lv[4];
  float m0 = -1e30f;
#pragma unroll
  for (int i = 0; i < 4; ++i) {
    size_t pi = (size_t)(i * 256 + bh) * 128 + t;
    mv[i] = pml[pi * 2];
    lv[i] = pml[pi * 2 + 1];
    m0 = fmaxf(m0, mv[i]);
  }
  float L = 0.f, accd = 0.f;
#pragma unroll
  for (int i = 0; i < 4; ++i) {
    size_t pi = (size_t)(i * 256 + bh) * 128 + t;
    float e = __expf(mv[i] - m0);
    L += lv[i] * e;
    accd += pacc[pi * 64 + lane] * e;
  }
  float v = accd / L;
  size_t off = (size_t)41280 * 512 + ((size_t)(b * 128 + t) * 512 + h * 64 + lane);
  if (*flag) ((float*)outp)[off] = v; else ((u16*)outp)[off] = f2b(v);
}

extern "C" void kernel_launch(void* const* d_in, const int* in_sizes, int n_in,
                              void* d_out, int out_size, void* d_ws, size_t ws_size,
                              hipStream_t stream) {
  (void)out_size; (void)ws_size;
  char* ws = (char*)d_ws;
  size_t off = 0;
  auto alloc = [&](size_t bytes) {
    char* p = ws + off;
    off += (bytes + 255) & ~(size_t)255;
    return (void*)p;
  };

  int* flag = (int*)alloc(256);

  size_t aoffs[32];
  size_t total = 0;
  for (int i = 0; i < n_in; ++i) {
    aoffs[i] = total;
    total += ((size_t)in_sizes[i] + 127) & ~(size_t)127;
  }
  u16* arena = (u16*)alloc(total * 2);

  const u16* c_ipts = arena + aoffs[0];
  const u16* c_mem  = arena + aoffs[1];
  const u16* c_Wq = arena + aoffs[2];  const u16* c_bq = arena + aoffs[3];
  const u16* c_Wk = arena + aoffs[4];  const u16* c_bk = arena + aoffs[5];
  const u16* c_Wv = arena + aoffs[6];  const u16* c_bv = arena + aoffs[7];
  const u16* c_Wm = arena + aoffs[8];  const u16* c_bm = arena + aoffs[9];
  const u16* c_g1 = arena + aoffs[10]; const u16* c_b1 = arena + aoffs[11];
  const u16* c_g2 = arena + aoffs[12]; const u16* c_b2 = arena + aoffs[13];
  const u16* c_Wp = arena + aoffs[14]; const u16* c_bp = arena + aoffs[15];
  const u16* c_repw = arena + aoffs[16];
  const u16* c_Wig = arena + aoffs[17]; const u16* c_big = arena + aoffs[18];
  const u16* c_Wmg = arena + aoffs[19]; const u16* c_bmg = arena + aoffs[20];
  const u16* c_fb = arena + aoffs[21];
  const u16* c_ib = arena + aoffs[22];

  u16* WqkvT = (u16*)alloc((size_t)1536 * 512 * 2);  // rows: Wq^T | Wk^T | Wv^T
  u16* WmT = (u16*)alloc(512 * 512 * 2);
  u16* WpT = (u16*)alloc(512 * 512 * 2);
  u16* WigT = (u16*)alloc(512 * 1024 * 2);
  u16* WmgT = (u16*)alloc(512 * 1024 * 2);
  u16* bqkv = (u16*)alloc(1536 * 2);
  u16* bkv = (u16*)alloc(1024 * 2);
  u16* inp = (u16*)alloc((size_t)4096 * 512 * 2);
  u16* qkvbuf = (u16*)alloc((size_t)4096 * 1536 * 2);  // [row][q|k|v]
  u16* rmean = (u16*)alloc(32 * 512 * 2);
  u16* gi = (u16*)alloc(32 * 1024 * 2);
  u16* membf = (u16*)alloc((size_t)41280 * 512 * 2);
  u16* qbuf = (u16*)alloc((size_t)41280 * 512 * 2);
  u16* obuf = (u16*)alloc((size_t)41280 * 512 * 2);   // + gmbuf = contiguous 84.5MB region
  u16* gmbuf = (u16*)alloc((size_t)41280 * 512 * 2);
  u16* nmbf = (u16*)alloc((size_t)41280 * 512 * 2);
  (void)gmbuf;
  u16* kvbuf = obuf;    // [41280][1024] spans obuf+gmbuf (both free at that point)
  float* pacc = (float*)(void*)qbuf;  // 33.5MB (qbuf dead after gemm_gates)
  float* pml = (float*)((char*)(void*)qbuf + (size_t)4 * 32768 * 64 * 4);

  detect_kernel<<<1, 64, 0, stream>>>((const u16*)d_in[0], flag);
  {
    CvtArgs ca;
    for (int i = 0; i < 23; ++i) {
      int ii = (i < n_in) ? i : (n_in - 1);
      ca.src[i] = d_in[ii];
      ca.aoff[i] = (int)aoffs[ii];
      ca.n[i] = in_sizes[ii];
    }
    ca.total = (int)total;
    convert_fused<<<(unsigned)((total / 4 + 255) / 256), 256, 0, stream>>>(ca, arena, flag);
  }
  biascat_kernel<<<1, 512, 0, stream>>>(c_bq, c_bk, c_bv, bqkv, bkv);

  transpose_kernel<<<dim3(16, 16), 256, 0, stream>>>(c_Wq, WqkvT, 512, 512);
  transpose_kernel<<<dim3(16, 16), 256, 0, stream>>>(c_Wk, WqkvT + (size_t)512 * 512, 512, 512);
  transpose_kernel<<<dim3(16, 16), 256, 0, stream>>>(c_Wv, WqkvT + (size_t)1024 * 512, 512, 512);
  transpose_kernel<<<dim3(16, 16), 256, 0, stream>>>(c_Wm, WmT, 512, 512);
  transpose_kernel<<<dim3(16, 16), 256, 0, stream>>>(c_Wp, WpT, 512, 512);
  transpose_kernel<<<dim3(32, 16), 256, 0, stream>>>(c_Wig, WigT, 512, 1024);
  transpose_kernel<<<dim3(32, 16), 256, 0, stream>>>(c_Wmg, WmgT, 512, 1024);

  gemm_bt<0><<<dim3(32 * 4), 256, 0, stream>>>(c_ipts, WpT, c_bp, inp, 4096, 512, 4);
  // fused QKV projection of inp: [4096][1536] = inp @ [Wq|Wk|Wv]
  gemm_bt<0><<<dim3(32 * 12), 256, 0, stream>>>(inp, WqkvT, bqkv, qkvbuf, 4096, 1536, 12);

  redmean_kernel<<<dim3(32, 2), 256, 0, stream>>>(inp, c_repw, rmean);
  gemm_bt<0><<<dim3(1 * 8), 256, 0, stream>>>(rmean, WigT, c_big, gi, 32, 1024, 8);

  const u16* memsrc = c_mem;
  for (int it = 0; it < 4; ++it) {
    gemm_bt<0><<<dim3(323 * 4), 256, 0, stream>>>(memsrc, WqkvT, c_bq, qbuf, 41280, 512, 4);
    attn1_mfma<<<dim3(11, 256), 256, 0, stream>>>(qbuf, qkvbuf + 512, qkvbuf + 1024, obuf, 1536);
    ln_kernel<<<dim3(10320), 256, 0, stream>>>(memsrc, obuf, membf, c_g1, c_b1);
    // fused mlp1 + mlp2 + residual + ln2, in-place on membf
    gemm_mlp_ln<<<dim3(645), 256, 0, stream>>>(membf, WmT, c_bm, c_g2, c_b2);
    memsrc = membf;
  }

  tanhmem_kernel<<<dim3(2641920 / 256), 256, 0, stream>>>(c_mem, qbuf, 2641920);
  // fused gate GEMM + gates: reads tanh(mem), Wmg(both halves), membf, c_mem;
  // writes next_memory (nmbf) + d_out directly. No gm round-trip.
  gemm_gates<<<dim3(323 * 8), 256, 0, stream>>>(qbuf, WmgT, c_bmg, gi, membf, c_mem,
                                                c_ib, c_fb, nmbf, d_out, flag, 41280);

  // fused K/V projection of next_memory: [41280][1024] = nmbf @ [Wk|Wv]
  gemm_bt<0><<<dim3(323 * 8), 256, 0, stream>>>(nmbf, WqkvT + (size_t)512 * 512, bkv,
                                                kvbuf, 41280, 1024, 8);
  attn2_mfma<<<dim3(256, 4), 256, 0, stream>>>(qkvbuf, kvbuf, kvbuf + 512, pacc, pml,
                                               1536, 1024);
  attn2_merge<<<dim3(32768), 64, 0, stream>>>(pacc, pml, d_out, flag);
}

// Round 8
// 1567.304 us; speedup vs baseline: 1.1261x; 1.1261x over previous
//
#include <hip/hip_runtime.h>
#include <stdint.h>

typedef uint16_t u16;
typedef uint32_t u32;

#define DEVI __device__ __forceinline__

DEVI float b2f(u16 u) { return __uint_as_float(((u32)u) << 16); }
DEVI float blo(u32 u) { return __uint_as_float(u << 16); }
DEVI float bhi(u32 u) { return __uint_as_float(u & 0xffff0000u); }
DEVI u16 f2b(float f) {
  u32 x = __float_as_uint(f);
  return (u16)((x + 0x7fffu + ((x >> 16) & 1u)) >> 16);
}
DEVI u32 pack2(float a, float b) { return (u32)f2b(a) | ((u32)f2b(b) << 16); }
DEVI float sigm(float x) { return 1.f / (1.f + __expf(-x)); }
// fast tanh: exact at +-inf, ~1e-6 rel error (bf16 output rounds at 2^-8)
DEVI float ftanh(float x) { return 1.f - 2.f / (1.f + __expf(2.f * x)); }

typedef __bf16 bf16x8 __attribute__((ext_vector_type(8)));
typedef float f32x4 __attribute__((ext_vector_type(4)));

#define MFMA16(a, b, c) __builtin_amdgcn_mfma_f32_16x16x32_bf16(a, b, c, 0, 0, 0)

DEVI void gll16(const void* g, void* l) {
  __builtin_amdgcn_global_load_lds((const __attribute__((address_space(1))) void*)g,
                                   (__attribute__((address_space(3))) void*)l, 16, 0, 0);
}

// monotonic total-order map for f32 bits
DEVI u32 fmono(float s) {
  u32 x = __float_as_uint(s);
  return x ^ (((u32)((int)x >> 31)) | 0x80000000u);
}

// descending compare-exchange (max to lower index)
DEVI void ced(u32& a, u32& b) {
  u32 hi = max(a, b), lo = min(a, b);
  a = hi; b = lo;
}
// Batcher odd-even merge sort, 8 elems, descending (19 CE)
DEVI void sort8_desc(u32* v) {
  ced(v[0], v[1]); ced(v[2], v[3]); ced(v[4], v[5]); ced(v[6], v[7]);
  ced(v[0], v[2]); ced(v[1], v[3]); ced(v[4], v[6]); ced(v[5], v[7]);
  ced(v[1], v[2]); ced(v[5], v[6]);
  ced(v[0], v[4]); ced(v[1], v[5]); ced(v[2], v[6]); ced(v[3], v[7]);
  ced(v[2], v[4]); ced(v[3], v[5]);
  ced(v[1], v[2]); ced(v[3], v[4]); ced(v[5], v[6]);
}
// bitonic 8-sequence -> descending sorted (12 CE)
DEVI void bitonic8_desc(u32* v) {
  ced(v[0], v[4]); ced(v[1], v[5]); ced(v[2], v[6]); ced(v[3], v[7]);
  ced(v[0], v[2]); ced(v[1], v[3]); ced(v[4], v[6]); ced(v[5], v[7]);
  ced(v[0], v[1]); ced(v[2], v[3]); ced(v[4], v[5]); ced(v[6], v[7]);
}
// a,b desc-sorted 8-lists -> a = top-8 of union, desc sorted
DEVI void merge_top8(u32* a, const u32* b) {
#pragma unroll
  for (int j = 0; j < 8; ++j) a[j] = max(a[j], b[7 - j]);
  bitonic8_desc(a);
}

// ---------------- input dtype detect: 0 = bf16, 1 = fp32 ----------------
__global__ void detect_kernel(const u16* __restrict__ x, int* __restrict__ flag) {
  if (threadIdx.x == 0 && blockIdx.x == 0) {
    int f = 0;
    for (int i = 0; i < 64; ++i) {
      u16 u = x[2 * i];  // low half if fp32
      int e = (u >> 7) & 0xFF;
      if (e > 131) f = 1;  // |val| >= 32 impossible for randn bf16
    }
    *flag = f;
  }
}

// ---------------- fused convert: all inputs -> bf16 arena, one dispatch ----------------
struct CvtArgs {
  const void* src[23];
  int aoff[23];
  int n[23];
  int total;
};

__global__ __launch_bounds__(256) void convert_fused(CvtArgs a, u16* __restrict__ arena,
                                                     const int* __restrict__ flag) {
  int e4 = (blockIdx.x * 256 + threadIdx.x) * 4;
  if (e4 >= a.total) return;
  const char* sp = (const char*)a.src[0];
  int rel = e4, cnt = a.n[0];
#pragma unroll
  for (int j = 1; j < 23; ++j)
    if (e4 >= a.aoff[j]) { sp = (const char*)a.src[j]; rel = e4 - a.aoff[j]; cnt = a.n[j]; }
  const bool f32 = (*flag != 0);
  if (rel + 3 < cnt) {
    if (f32) {
      float4 v = *(const float4*)(sp + (size_t)rel * 4);
      uint2 o;
      o.x = pack2(v.x, v.y);
      o.y = pack2(v.z, v.w);
      *(uint2*)(arena + e4) = o;
    } else {
      *(uint2*)(arena + e4) = *(const uint2*)(sp + (size_t)rel * 2);
    }
  } else {
#pragma unroll
    for (int k = 0; k < 4; ++k) {
      u16 o = 0;
      if (rel + k < cnt)
        o = f32 ? f2b(((const float*)sp)[rel + k]) : ((const u16*)sp)[rel + k];
      arena[e4 + k] = o;
    }
  }
}

// ---------------- bias concat: bqkv=[bq|bk|bv], bkv=[bk|bv] ----------------
__global__ void biascat_kernel(const u16* __restrict__ bq, const u16* __restrict__ bk,
                               const u16* __restrict__ bv, u16* __restrict__ bqkv,
                               u16* __restrict__ bkv) {
  int t = threadIdx.x;  // 512
  bqkv[t] = bq[t];
  bqkv[512 + t] = bk[t];
  bqkv[1024 + t] = bv[t];
  bkv[t] = bk[t];
  bkv[512 + t] = bv[t];
}

// ---------------- GEMM: m97 pattern + XCD swizzle + coalesced epilogue + 2-PHASE PIPELINE --
// BK=32, double-buffered staging (2x16KB). Epilogue staging uses XOR-chunk swizzle instead
// of +8 pad -> LDS exactly 32KB -> 5 blocks/CU (was 4). Numerics identical.
template <int ACT>
__global__ __launch_bounds__(256, 5) void gemm_bt(
    const u16* __restrict__ A, const u16* __restrict__ Bt,
    const u16* __restrict__ bias, u16* __restrict__ Co, int Mtot, int Ntot, int nby) {
  __shared__ __align__(16) u16 smem[128 * 128];  // staging dbuf (32KB) / epilogue st (32KB)
  u16* const aB0 = smem;
  u16* const aB1 = smem + 4096;
  u16* const bB0 = smem + 8192;
  u16* const bB1 = smem + 12288;
  const int tid = threadIdx.x;
  const int lane = tid & 63;
  const int w = tid >> 6;
  const int quad = lane >> 4;
  const int l15 = lane & 15;

  const int nwg = gridDim.x;
  const int orig = blockIdx.x;
  const int xcd = orig & 7, sq = orig >> 3;
  const int qd = nwg >> 3, rm = nwg & 7;
  const int wg = (xcd < rm ? xcd * (qd + 1) : rm * (qd + 1) + (xcd - rm) * qd) + sq;
  const int m0 = (wg / nby) * 128;
  const int n0 = (wg % nby) * 128;

  const int wm = (w & 1) << 6;
  const int wn = (w >> 1) << 6;

  f32x4 acc[4][4] = {};

  const u16* ga[2];
  const u16* gb[2];
#pragma unroll
  for (int q = 0; q < 2; ++q) {
    int j = q * 256 + tid;
    int r = j >> 2, s = j & 3;
    int c = (s ^ ((r >> 1) & 3)) * 8;
    int ra = m0 + r;
    if (ra >= Mtot) ra = Mtot - 1;
    ga[q] = A + (size_t)ra * 512 + c;
    gb[q] = Bt + (size_t)(n0 + r) * 512 + c;
  }

  auto stage = [&](int p, int ko) {
    u16* ab = p ? aB1 : aB0;
    u16* bb = p ? bB1 : bB0;
#pragma unroll
    for (int q = 0; q < 2; ++q) {
      int j = q * 256 + tid;
      gll16(ga[q] + ko * 32, ab + j * 8);
      gll16(gb[q] + ko * 32, bb + j * 8);
    }
  };

  stage(0, 0);
  __syncthreads();
  int cur = 0;
  for (int ko = 0; ko < 16; ++ko) {
    if (ko < 15) stage(cur ^ 1, ko + 1);
    u16* ab = cur ? aB1 : aB0;
    u16* bb = cur ? bB1 : bB0;
    bf16x8 af[4], bfr[4];
#pragma unroll
    for (int i = 0; i < 4; ++i) {
      int r = wm + i * 16 + l15;
      af[i] = *(const bf16x8*)(ab + (((r << 2) | (quad ^ ((r >> 1) & 3)))) * 8);
      int rn = wn + i * 16 + l15;
      bfr[i] = *(const bf16x8*)(bb + (((rn << 2) | (quad ^ ((rn >> 1) & 3)))) * 8);
    }
#pragma unroll
    for (int i = 0; i < 4; ++i)
#pragma unroll
      for (int jn = 0; jn < 4; ++jn)
        acc[i][jn] = MFMA16(af[i], bfr[jn], acc[i][jn]);
    __syncthreads();
    cur ^= 1;
  }

  // epilogue: bias/act -> bf16 into LDS (XOR-chunk swizzled), then coalesced 16B stores
  u16* st = smem;
#pragma unroll
  for (int jn = 0; jn < 4; ++jn) {
    int coll = wn + jn * 16 + l15;
    float bv = b2f(bias[n0 + coll]);
#pragma unroll
    for (int i = 0; i < 4; ++i) {
      int rowb = wm + i * 16 + quad * 4;
#pragma unroll
      for (int rr = 0; rr < 4; ++rr) {
        float vv = acc[i][jn][rr] + bv;
        if (ACT) vv = fmaxf(vv, 0.f);
        int rowx = rowb + rr;
        st[rowx * 128 + ((((coll >> 3) ^ (rowx & 7)) << 3) | (coll & 7))] = f2b(vv);
      }
    }
  }
  __syncthreads();
#pragma unroll
  for (int t = 0; t < 8; ++t) {
    int idx = (t * 256 + tid) * 8;  // u16 units within 128x128 tile
    int r = idx >> 7;
    int c = idx & 127;  // multiple of 8
    int row = m0 + r;
    if (row < Mtot) {
      uint4 v = *(const uint4*)(st + r * 128 + (((c >> 3) ^ (r & 7)) << 3));
      *(uint4*)(Co + (size_t)row * Ntot + n0 + c) = v;
    }
  }
}

// ---------------- gate GEMM + gates fused (2-phase pipelined, 32KB LDS) ----------------
__global__ __launch_bounds__(256, 5) void gemm_gates(
    const u16* __restrict__ A, const u16* __restrict__ WmgTp,
    const u16* __restrict__ bmg, const u16* __restrict__ gi,
    const u16* __restrict__ memfin, const u16* __restrict__ mem_in,
    const u16* __restrict__ ibp, const u16* __restrict__ fbp,
    u16* __restrict__ nmbf, void* __restrict__ outp, const int* __restrict__ flag,
    int Mtot) {
  __shared__ __align__(16) u16 smem[128 * 128];
  u16* const aB0 = smem;
  u16* const aB1 = smem + 4096;
  u16* const bB0 = smem + 8192;
  u16* const bB1 = smem + 12288;
  const int tid = threadIdx.x;
  const int lane = tid & 63;
  const int w = tid >> 6;
  const int quad = lane >> 4;
  const int l15 = lane & 15;

  const int nwg = gridDim.x;
  const int orig = blockIdx.x;
  const int xcd = orig & 7, sq = orig >> 3;
  const int qd = nwg >> 3, rm = nwg & 7;
  const int wg = (xcd < rm ? xcd * (qd + 1) : rm * (qd + 1) + (xcd - rm) * qd) + sq;
  const int m0 = (wg >> 3) * 128;    // nby = 8
  const int n0h = (wg & 7) * 64;     // col offset within [0,512)

  const int wm = (w & 1) << 6;
  const int wn = (w >> 1) << 6;

  f32x4 acc[4][4] = {};

  const u16* ga[2];
  const u16* gb[2];
#pragma unroll
  for (int q = 0; q < 2; ++q) {
    int j = q * 256 + tid;
    int r = j >> 2, s = j & 3;
    int c = (s ^ ((r >> 1) & 3)) * 8;
    int ra = m0 + r;
    if (ra >= Mtot) ra = Mtot - 1;
    ga[q] = A + (size_t)ra * 512 + c;
    int br = (r < 64) ? (n0h + r) : (512 + n0h + r - 64);  // ig half | fg half
    gb[q] = WmgTp + (size_t)br * 512 + c;
  }

  auto stage = [&](int p, int ko) {
    u16* ab = p ? aB1 : aB0;
    u16* bb = p ? bB1 : bB0;
#pragma unroll
    for (int q = 0; q < 2; ++q) {
      int j = q * 256 + tid;
      gll16(ga[q] + ko * 32, ab + j * 8);
      gll16(gb[q] + ko * 32, bb + j * 8);
    }
  };

  stage(0, 0);
  __syncthreads();
  int cur = 0;
  for (int ko = 0; ko < 16; ++ko) {
    if (ko < 15) stage(cur ^ 1, ko + 1);
    u16* ab = cur ? aB1 : aB0;
    u16* bb = cur ? bB1 : bB0;
    bf16x8 af[4], bfr[4];
#pragma unroll
    for (int i = 0; i < 4; ++i) {
      int r = wm + i * 16 + l15;
      af[i] = *(const bf16x8*)(ab + (((r << 2) | (quad ^ ((r >> 1) & 3)))) * 8);
      int rn = wn + i * 16 + l15;
      bfr[i] = *(const bf16x8*)(bb + (((rn << 2) | (quad ^ ((rn >> 1) & 3)))) * 8);
    }
#pragma unroll
    for (int i = 0; i < 4; ++i)
#pragma unroll
      for (int jn = 0; jn < 4; ++jn)
        acc[i][jn] = MFMA16(af[i], bfr[jn], acc[i][jn]);
    __syncthreads();
    cur ^= 1;
  }

  // stage gm (bf16, with bmg bias) into LDS (swizzled): cols 0..63 = ig, 64..127 = fg
  u16* st = smem;
#pragma unroll
  for (int jn = 0; jn < 4; ++jn) {
    int coll = wn + jn * 16 + l15;
    int bcol = (coll < 64) ? (n0h + coll) : (512 + n0h + coll - 64);
    float bv = b2f(bmg[bcol]);
#pragma unroll
    for (int i = 0; i < 4; ++i) {
      int rowb = wm + i * 16 + quad * 4;
#pragma unroll
      for (int rr = 0; rr < 4; ++rr) {
        int rowx = rowb + rr;
        st[rowx * 128 + ((((coll >> 3) ^ (rowx & 7)) << 3) | (coll & 7))] =
            f2b(acc[i][jn][rr] + bv);
      }
    }
  }
  __syncthreads();

  const float ib = b2f(ibp[0]);
  const float fb = b2f(fbp[0]);
  const bool of32 = (*flag != 0);
#pragma unroll
  for (int t = 0; t < 4; ++t) {
    int chunk = t * 256 + tid;        // 1024 chunks of 8 elems = 128 rows x 64 cols
    int rl = chunk >> 3;
    int c8 = (chunk & 7) * 8;
    int row = m0 + rl;
    if (row >= Mtot) continue;
    int b = row / 1290;
    size_t gidx = (size_t)row * 512 + n0h + c8;
    uint4 uig = *(const uint4*)(st + rl * 128 + (((c8 >> 3) ^ (rl & 7)) << 3));
    uint4 ufg = *(const uint4*)(st + rl * 128 + ((((c8 >> 3) + 8) ^ (rl & 7)) << 3));
    uint4 ugi = *(const uint4*)(gi + b * 1024 + n0h + c8);
    uint4 ugf = *(const uint4*)(gi + b * 1024 + 512 + n0h + c8);
    uint4 umf = *(const uint4*)(memfin + gidx);
    uint4 umi = *(const uint4*)(mem_in + gidx);
    const u32* pig = (const u32*)&uig;
    const u32* pfg = (const u32*)&ufg;
    const u32* pgi = (const u32*)&ugi;
    const u32* pgf = (const u32*)&ugf;
    const u32* pmf = (const u32*)&umf;
    const u32* pmi = (const u32*)&umi;
    float v[8];
#pragma unroll
    for (int k = 0; k < 4; ++k) {
      float ig0 = sigm(blo(pig[k]) + blo(pgi[k]) + ib);
      float ig1 = sigm(bhi(pig[k]) + bhi(pgi[k]) + ib);
      float fg0 = sigm(blo(pfg[k]) + blo(pgf[k]) + fb);
      float fg1 = sigm(bhi(pfg[k]) + bhi(pgf[k]) + fb);
      v[2 * k] = ig0 * ftanh(blo(pmf[k])) + fg0 * blo(pmi[k]);
      v[2 * k + 1] = ig1 * ftanh(bhi(pmf[k])) + fg1 * bhi(pmi[k]);
    }
    uint4 o;
    u32* po = (u32*)&o;
#pragma unroll
    for (int k = 0; k < 4; ++k) po[k] = pack2(v[2 * k], v[2 * k + 1]);
    *(uint4*)(nmbf + gidx) = o;
    if (of32) {
      float4 f0, f1;
      f0.x = v[0]; f0.y = v[1]; f0.z = v[2]; f0.w = v[3];
      f1.x = v[4]; f1.y = v[5]; f1.z = v[6]; f1.w = v[7];
      *(float4*)((float*)outp + gidx) = f0;
      *(float4*)((float*)outp + gidx + 4) = f1;
    } else {
      *(uint4*)((u16*)outp + gidx) = o;
    }
  }
}

// ---------------- weight transpose ----------------
__global__ __launch_bounds__(256) void transpose_kernel(const u16* __restrict__ in,
                                                        u16* __restrict__ outb, int K, int N) {
  __shared__ u16 tile[32][33];
  const int tx = threadIdx.x & 31, ty = threadIdx.x >> 5;
  const int bx = blockIdx.x * 32;
  const int by = blockIdx.y * 32;
#pragma unroll
  for (int i = 0; i < 32; i += 8) tile[ty + i][tx] = in[(size_t)(by + ty + i) * N + bx + tx];
  __syncthreads();
#pragma unroll
  for (int i = 0; i < 32; i += 8) outb[(size_t)(bx + ty + i) * K + by + tx] = tile[tx][ty + i];
}

// ---------------- tanh(memory) ----------------
__global__ void tanhmem_kernel(const u16* __restrict__ mi, u16* __restrict__ th, int n8) {
  int i = blockIdx.x * 256 + threadIdx.x;
  if (i >= n8) return;
  uint4 u = ((const uint4*)mi)[i];
  uint4 t;
  t.x = pack2(ftanh(blo(u.x)), ftanh(bhi(u.x)));
  t.y = pack2(ftanh(blo(u.y)), ftanh(bhi(u.y)));
  t.z = pack2(ftanh(blo(u.z)), ftanh(bhi(u.z)));
  t.w = pack2(ftanh(blo(u.w)), ftanh(bhi(u.w)));
  ((uint4*)th)[i] = t;
}

// ---------------- rmean ----------------
__global__ void redmean_kernel(const u16* __restrict__ inp, const u16* __restrict__ repw,
                               u16* __restrict__ outb) {
  const int b = blockIdx.x;
  const int c = blockIdx.y * 256 + threadIdx.x;
  const float rw = b2f(repw[c]);
  float s = 0.f;
  for (int t = 0; t < 128; ++t)
    s += fmaxf(rw * b2f(inp[(size_t)(b * 128 + t) * 512 + c]), 0.f);
  outb[b * 512 + c] = f2b(s * (1.f / 128.f));
}

// ---------------- LayerNorm (4 rows/block, 1 wave per row) ----------------
__global__ __launch_bounds__(256) void ln_kernel(const u16* __restrict__ src,
                                                 const u16* __restrict__ addb,
                                                 u16* __restrict__ dst,
                                                 const u16* __restrict__ g,
                                                 const u16* __restrict__ bb) {
  const int row = blockIdx.x * 4 + (threadIdx.x >> 6);
  const int lane = threadIdx.x & 63;
  const u16* srow = src + (size_t)row * 512;
  const u16* arow = addb + (size_t)row * 512;
  float x[8];
  float s = 0.f;
#pragma unroll
  for (int i = 0; i < 8; ++i) {
    int c = lane + i * 64;
    x[i] = b2f(srow[c]) + b2f(arow[c]);
    s += x[i];
  }
#pragma unroll
  for (int off = 32; off > 0; off >>= 1) s += __shfl_xor(s, off, 64);
  const float mu = s * (1.f / 512.f);
  float v = 0.f;
#pragma unroll
  for (int i = 0; i < 8; ++i) {
    float d = x[i] - mu;
    v = fmaf(d, d, v);
  }
#pragma unroll
  for (int off = 32; off > 0; off >>= 1) v += __shfl_xor(v, off, 64);
  const float rstd = rsqrtf(v * (1.f / 512.f) + 1e-5f);
  u16* orow = dst + (size_t)row * 512;
#pragma unroll
  for (int i = 0; i < 8; ++i) {
    int c = lane + i * 64;
    orow[c] = f2b(fmaf((x[i] - mu) * rstd, b2f(g[c]), b2f(bb[c])));
  }
}

// ---------------- attention 1 (MFMA): 1290 q (mem), 128 k (inp), top-8 mask ----------------
__global__ __launch_bounds__(256, 3) void attn1_mfma(const u16* __restrict__ q,
                                                     const u16* __restrict__ kb,
                                                     const u16* __restrict__ vb,
                                                     u16* __restrict__ o, int ldkv) {
  __shared__ __align__(16) u16 Pl[128 * 136];  // masked P [q][k]; rows 0..60 alias Kl
  __shared__ __align__(16) u16 VT[64 * 136];   // V^T [d][k]
  __shared__ float lbuf[128];                  // 1/l per local query
  u16* Kl = Pl;                                // phase-1 alias: swizzled K [key][dim]

  const int tid = threadIdx.x;
  const int lane = tid & 63;
  const int w = tid >> 6;
  const int quad = lane >> 4;
  const int l15 = lane & 15;
  const int qb = blockIdx.x;
  const int bh = blockIdx.y;
  const int b = bh >> 3, h = bh & 7;

  // stage K swizzled (gll16) into Kl
#pragma unroll
  for (int qq = 0; qq < 4; ++qq) {
    int j = qq * 256 + tid;
    int r = j >> 3, s = j & 7;
    gll16(kb + (size_t)(b * 128 + r) * ldkv + h * 64 + (s ^ (r & 7)) * 8, Kl + j * 8);
  }
  // stage V transposed: per wave, 64 consecutive keys per d-row write (2-way banks, free)
#pragma unroll
  for (int p = 0; p < 4; ++p) {
    int key = (tid & 63) + 64 * (p & 1);
    int dc = w + 4 * (p >> 1);
    uint4 u = *(const uint4*)(vb + (size_t)(b * 128 + key) * ldkv + h * 64 + dc * 8);
    u16 tmp[8];
    *(uint4*)tmp = u;
#pragma unroll
    for (int jj = 0; jj < 8; ++jj) VT[(dc * 8 + jj) * 136 + key] = tmp[jj];
  }

  // Q fragments (B-operand): col = query, quad picks dim-chunk
  bf16x8 bq[2][2];
  {
    int ra = min(qb * 128 + w * 32 + l15, 1289);
    int rb_ = min(qb * 128 + w * 32 + 16 + l15, 1289);
    const u16* qa = q + (size_t)(b * 1290 + ra) * 512 + h * 64 + quad * 8;
    const u16* qc = q + (size_t)(b * 1290 + rb_) * 512 + h * 64 + quad * 8;
    bq[0][0] = *(const bf16x8*)(qa);
    bq[0][1] = *(const bf16x8*)(qa + 32);
    bq[1][0] = *(const bf16x8*)(qc);
    bq[1][1] = *(const bf16x8*)(qc + 32);
  }
  __syncthreads();

  // S^T = K.Q^T : thread holds query (w*32+i*16+l15), k = jn*16+quad*4+rr
  f32x4 sa[2][8] = {};
#pragma unroll
  for (int ks = 0; ks < 2; ++ks) {
#pragma unroll
    for (int jn = 0; jn < 8; ++jn) {
      int n = jn * 16 + l15;
      int cch = ks * 4 + quad;
      bf16x8 ak = *(const bf16x8*)(Kl + (n * 8 + (cch ^ (n & 7))) * 8);
      sa[0][jn] = MFMA16(ak, bq[0][ks], sa[0][jn]);
      sa[1][jn] = MFMA16(ak, bq[1][ks], sa[1][jn]);
    }
  }
  __syncthreads();  // all Kl reads done before P overwrites the aliased region

  const u32 ibase = 127u - (u32)(quad * 4);
#pragma unroll
  for (int i = 0; i < 2; ++i) {
    const int qi = w * 32 + i * 16 + l15;
    // build packed keys (scale scores in place; sa keeps f32 for the exp pass)
    u32 g[4][8];
#pragma unroll
    for (int jn = 0; jn < 8; ++jn)
#pragma unroll
      for (int rr = 0; rr < 4; ++rr) {
        float s = sa[i][jn][rr] * 0.125f;
        sa[i][jn][rr] = s;
        g[jn >> 1][(jn & 1) * 4 + rr] =
            (fmono(s) & 0xFFFFFF80u) | (ibase - (u32)(jn * 16 + rr));
      }
    // local top-8: 4x sort8 + merge tree
    sort8_desc(g[0]); sort8_desc(g[1]); sort8_desc(g[2]); sort8_desc(g[3]);
    merge_top8(g[0], g[1]);
    merge_top8(g[2], g[3]);
    merge_top8(g[0], g[2]);
    u32* tv = g[0];
    // merge sorted top-8 lists across quads (xor 16, then 32)
#pragma unroll
    for (int off = 16; off < 64; off <<= 1) {
      u32 pv[8];
#pragma unroll
      for (int j = 0; j < 8; ++j) pv[j] = (u32)__shfl_xor((int)tv[7 - j], off, 64);
#pragma unroll
      for (int j = 0; j < 8; ++j) tv[j] = max(tv[j], pv[j]);
      bitonic8_desc(tv);
    }
    const u32 t8 = tv[7];  // 8th largest packed key; membership = (key >= t8)
    // decode running max (25-bit truncated; <= true max, safe for exp)
    u32 mb = tv[0] & 0xFFFFFF80u;
    u32 xm = (mb & 0x80000000u) ? (mb ^ 0x80000000u) : ~mb;
    const float mx = __uint_as_float(xm);
    // single pass: denom over all 128 + masked unnormalized P write
    float lsum = 0.f;
#pragma unroll
    for (int jn = 0; jn < 8; ++jn) {
      u16 pr[4];
#pragma unroll
      for (int rr = 0; rr < 4; ++rr) {
        float s = sa[i][jn][rr];
        float e = __expf(s - mx);
        lsum += e;
        u32 kk = (fmono(s) & 0xFFFFFF80u) | (ibase - (u32)(jn * 16 + rr));
        pr[rr] = (kk >= t8) ? f2b(e) : (u16)0;
      }
      uint2 st;
      st.x = (u32)pr[0] | ((u32)pr[1] << 16);
      st.y = (u32)pr[2] | ((u32)pr[3] << 16);
      *(uint2*)(Pl + qi * 136 + jn * 16 + quad * 4) = st;
    }
    lsum += __shfl_xor(lsum, 16, 64);
    lsum += __shfl_xor(lsum, 32, 64);
    if (quad == 0) lbuf[qi] = 1.f / lsum;
  }
  __syncthreads();

  // O = P.V  (A = masked P rows, B = VT rows)
  f32x4 oa[2][4] = {};
#pragma unroll
  for (int kc = 0; kc < 4; ++kc) {
    bf16x8 ap[2];
#pragma unroll
    for (int i = 0; i < 2; ++i)
      ap[i] = *(const bf16x8*)(Pl + (w * 32 + i * 16 + l15) * 136 + kc * 32 + quad * 8);
#pragma unroll
    for (int jd = 0; jd < 4; ++jd) {
      bf16x8 bv_ = *(const bf16x8*)(VT + (jd * 16 + l15) * 136 + kc * 32 + quad * 8);
      oa[0][jd] = MFMA16(ap[0], bv_, oa[0][jd]);
      oa[1][jd] = MFMA16(ap[1], bv_, oa[1][jd]);
    }
  }

  // epilogue: scale rows by 1/l, write bf16
#pragma unroll
  for (int i = 0; i < 2; ++i) {
    int rowl = w * 32 + i * 16 + quad * 4;
#pragma unroll
    for (int rr = 0; rr < 4; ++rr) {
      int qg = qb * 128 + rowl + rr;
      if (qg < 1290) {
        float il = lbuf[rowl + rr];
        u16* orow = o + (size_t)(b * 1290 + qg) * 512 + h * 64;
#pragma unroll
        for (int jd = 0; jd < 4; ++jd) orow[jd * 16 + l15] = f2b(oa[i][jd][rr] * il);
      }
    }
  }
}

// ---------------- attention 2 (MFMA flash): 128 q (inp), 1290 k (next_memory) ----------------
__global__ __launch_bounds__(256, 2) void attn2_mfma(const u16* __restrict__ q2,
                                                     const u16* __restrict__ k2,
                                                     const u16* __restrict__ v2,
                                                     float* __restrict__ pacc,
                                                     float* __restrict__ pml,
                                                     int ldq, int ldkv) {
  __shared__ __align__(16) u16 Kl[64 * 64];      // swizzled [key][dim]
  __shared__ __align__(16) u16 VT[64 * 72];      // [dim][key], stride 72
  __shared__ __align__(16) u16 Pl[4 * 32 * 72];  // per-wave P [32q][64k]
  const int tid = threadIdx.x;
  const int lane = tid & 63;
  const int w = tid >> 6;
  const int quad = lane >> 4;
  const int l15 = lane & 15;
  const int bh = blockIdx.x;
  const int b = bh >> 3, h = bh & 7;
  const int part = blockIdx.y;
  const int kstart = (part * 1290) >> 2;
  const int kend = ((part + 1) * 1290) >> 2;

  bf16x8 aq[2][2];
  {
    int r0 = b * 128 + w * 32 + l15;
    const u16* qa = q2 + (size_t)r0 * ldq + h * 64 + quad * 8;
    aq[0][0] = *(const bf16x8*)(qa);
    aq[0][1] = *(const bf16x8*)(qa + 32);
    aq[1][0] = *(const bf16x8*)(qa + (size_t)16 * ldq);
    aq[1][1] = *(const bf16x8*)(qa + (size_t)16 * ldq + 32);
  }

  f32x4 oa[2][4] = {};
  float m_[2][4], l_[2][4];
#pragma unroll
  for (int i = 0; i < 2; ++i)
#pragma unroll
    for (int r = 0; r < 4; ++r) { m_[i][r] = -1e30f; l_[i][r] = 0.f; }

  const int nk = kend - kstart;
  for (int kt = 0; kt < nk; kt += 64) {
    __syncthreads();
    // stage K swizzled (gll16)
#pragma unroll
    for (int qq = 0; qq < 2; ++qq) {
      int j = qq * 256 + tid;
      int r = j >> 3, s = j & 7;
      int kg = kstart + kt + r;
      if (kg >= kend) kg = kend - 1;
      gll16(k2 + (size_t)(b * 1290 + kg) * ldkv + h * 64 + (s ^ (r & 7)) * 8, Kl + j * 8);
    }
    // stage V transposed: lane r = key, dc = dim chunk (write banks: const + r/2 -> 2-way free)
    {
      int r = tid & 63;
      int kg = kstart + kt + r;
      if (kg >= kend) kg = kend - 1;
      const u16* vrow = v2 + (size_t)(b * 1290 + kg) * ldkv + h * 64;
#pragma unroll
      for (int p = 0; p < 2; ++p) {
        int dc = (tid >> 6) + p * 4;
        uint4 u = *(const uint4*)(vrow + dc * 8);
        u16 tmp[8];
        *(uint4*)tmp = u;
#pragma unroll
        for (int jj = 0; jj < 8; ++jj) VT[(dc * 8 + jj) * 72 + r] = tmp[jj];
      }
    }
    __syncthreads();

    // S = Q.K^T
    f32x4 sa[2][4] = {};
#pragma unroll
    for (int ks = 0; ks < 2; ++ks) {
#pragma unroll
      for (int jn = 0; jn < 4; ++jn) {
        int n = jn * 16 + l15;
        int cch = ks * 4 + quad;
        bf16x8 bk = *(const bf16x8*)(Kl + (n * 8 + (cch ^ (n & 7))) * 8);
        sa[0][jn] = MFMA16(aq[0][ks], bk, sa[0][jn]);
        sa[1][jn] = MFMA16(aq[1][ks], bk, sa[1][jn]);
      }
    }

    // online softmax (C-layout: col=l15 is key, row=quad*4+r is query) + P to LDS
    u16* pw = Pl + w * (32 * 72);
#pragma unroll
    for (int i = 0; i < 2; ++i) {
      float rmax[4] = {-1e30f, -1e30f, -1e30f, -1e30f};
#pragma unroll
      for (int jn = 0; jn < 4; ++jn) {
        int kg = kstart + kt + jn * 16 + l15;
        bool val = kg < kend;
#pragma unroll
        for (int r = 0; r < 4; ++r) {
          float s = sa[i][jn][r] * 0.125f;
          s = val ? s : -1e30f;
          sa[i][jn][r] = s;
          rmax[r] = fmaxf(rmax[r], s);
        }
      }
#pragma unroll
      for (int off = 1; off < 16; off <<= 1)
#pragma unroll
        for (int r = 0; r < 4; ++r) rmax[r] = fmaxf(rmax[r], __shfl_xor(rmax[r], off, 64));
      float alpha[4];
#pragma unroll
      for (int r = 0; r < 4; ++r) {
        float mn = fmaxf(m_[i][r], rmax[r]);
        alpha[r] = __expf(m_[i][r] - mn);
        m_[i][r] = mn;
      }
      float lsum[4] = {0.f, 0.f, 0.f, 0.f};
#pragma unroll
      for (int jn = 0; jn < 4; ++jn)
#pragma unroll
        for (int r = 0; r < 4; ++r) {
          float p = __expf(sa[i][jn][r] - m_[i][r]);
          sa[i][jn][r] = p;
          lsum[r] += p;
        }
#pragma unroll
      for (int off = 1; off < 16; off <<= 1)
#pragma unroll
        for (int r = 0; r < 4; ++r) lsum[r] += __shfl_xor(lsum[r], off, 64);
#pragma unroll
      for (int r = 0; r < 4; ++r) l_[i][r] = l_[i][r] * alpha[r] + lsum[r];
#pragma unroll
      for (int jd = 0; jd < 4; ++jd)
#pragma unroll
        for (int r = 0; r < 4; ++r) oa[i][jd][r] *= alpha[r];
#pragma unroll
      for (int jn = 0; jn < 4; ++jn) {
        int col = jn * 16 + l15;
#pragma unroll
        for (int r = 0; r < 4; ++r)
          pw[(i * 16 + quad * 4 + r) * 72 + col] = f2b(sa[i][jn][r]);
      }
    }

    // O += P.V   (A = P from per-wave LDS, B = VT)
#pragma unroll
    for (int ks = 0; ks < 2; ++ks) {
      bf16x8 ap[2];
#pragma unroll
      for (int i = 0; i < 2; ++i)
        ap[i] = *(const bf16x8*)(pw + (i * 16 + l15) * 72 + ks * 32 + quad * 8);
#pragma unroll
      for (int jd = 0; jd < 4; ++jd) {
        bf16x8 bv_ = *(const bf16x8*)(VT + (jd * 16 + l15) * 72 + ks * 32 + quad * 8);
        oa[0][jd] = MFMA16(ap[0], bv_, oa[0][jd]);
        oa[1][jd] = MFMA16(ap[1], bv_, oa[1][jd]);
      }
    }
  }

  // store partials (C-layout scatter)
  float* pa = pacc + (size_t)(part * 256 + bh) * 128 * 64;
#pragma unroll
  for (int i = 0; i < 2; ++i) {
    int row = w * 32 + i * 16 + quad * 4;
#pragma unroll
    for (int r = 0; r < 4; ++r)
#pragma unroll
      for (int jd = 0; jd < 4; ++jd)
        pa[(size_t)(row + r) * 64 + jd * 16 + l15] = oa[i][jd][r];
    if (l15 == 0) {
#pragma unroll
      for (int r = 0; r < 4; ++r) {
        size_t pi = (size_t)(part * 256 + bh) * 128 + row + r;
        pml[pi * 2 + 0] = m_[i][r];
        pml[pi * 2 + 1] = l_[i][r];
      }
    }
  }
}

__global__ __launch_bounds__(64) void attn2_merge(const float* __restrict__ pacc,
                                                  const float* __restrict__ pml,
                                                  void* __restrict__ outp,
                                                  const int* __restrict__ flag) {
  const int qi = blockIdx.x;  // bh*128 + t
  const int bh = qi >> 7, t = qi & 127;
  const int b = bh >> 3, h = bh & 7;
  const int lane = threadIdx.x;
  float mv[4], lv[4];
  float m0 = -1e30f;
#pragma unroll
  for (int i = 0; i < 4; ++i) {
    size_t pi = (size_t)(i * 256 + bh) * 128 + t;
    mv[i] = pml[pi * 2];
    lv[i] = pml[pi * 2 + 1];
    m0 = fmaxf(m0, mv[i]);
  }
  float L = 0.f, accd = 0.f;
#pragma unroll
  for (int i = 0; i < 4; ++i) {
    size_t pi = (size_t)(i * 256 + bh) * 128 + t;
    float e = __expf(mv[i] - m0);
    L += lv[i] * e;
    accd += pacc[pi * 64 + lane] * e;
  }
  float v = accd / L;
  size_t off = (size_t)41280 * 512 + ((size_t)(b * 128 + t) * 512 + h * 64 + lane);
  if (*flag) ((float*)outp)[off] = v; else ((u16*)outp)[off] = f2b(v);
}

extern "C" void kernel_launch(void* const* d_in, const int* in_sizes, int n_in,
                              void* d_out, int out_size, void* d_ws, size_t ws_size,
                              hipStream_t stream) {
  (void)out_size; (void)ws_size;
  char* ws = (char*)d_ws;
  size_t off = 0;
  auto alloc = [&](size_t bytes) {
    char* p = ws + off;
    off += (bytes + 255) & ~(size_t)255;
    return (void*)p;
  };

  int* flag = (int*)alloc(256);

  size_t aoffs[32];
  size_t total = 0;
  for (int i = 0; i < n_in; ++i) {
    aoffs[i] = total;
    total += ((size_t)in_sizes[i] + 127) & ~(size_t)127;
  }
  u16* arena = (u16*)alloc(total * 2);

  const u16* c_ipts = arena + aoffs[0];
  const u16* c_mem  = arena + aoffs[1];
  const u16* c_Wq = arena + aoffs[2];  const u16* c_bq = arena + aoffs[3];
  const u16* c_Wk = arena + aoffs[4];  const u16* c_bk = arena + aoffs[5];
  const u16* c_Wv = arena + aoffs[6];  const u16* c_bv = arena + aoffs[7];
  const u16* c_Wm = arena + aoffs[8];  const u16* c_bm = arena + aoffs[9];
  const u16* c_g1 = arena + aoffs[10]; const u16* c_b1 = arena + aoffs[11];
  const u16* c_g2 = arena + aoffs[12]; const u16* c_b2 = arena + aoffs[13];
  const u16* c_Wp = arena + aoffs[14]; const u16* c_bp = arena + aoffs[15];
  const u16* c_repw = arena + aoffs[16];
  const u16* c_Wig = arena + aoffs[17]; const u16* c_big = arena + aoffs[18];
  const u16* c_Wmg = arena + aoffs[19]; const u16* c_bmg = arena + aoffs[20];
  const u16* c_fb = arena + aoffs[21];
  const u16* c_ib = arena + aoffs[22];

  u16* WqkvT = (u16*)alloc((size_t)1536 * 512 * 2);  // rows: Wq^T | Wk^T | Wv^T
  u16* WmT = (u16*)alloc(512 * 512 * 2);
  u16* WpT = (u16*)alloc(512 * 512 * 2);
  u16* WigT = (u16*)alloc(512 * 1024 * 2);
  u16* WmgT = (u16*)alloc(512 * 1024 * 2);
  u16* bqkv = (u16*)alloc(1536 * 2);
  u16* bkv = (u16*)alloc(1024 * 2);
  u16* inp = (u16*)alloc((size_t)4096 * 512 * 2);
  u16* qkvbuf = (u16*)alloc((size_t)4096 * 1536 * 2);  // [row][q|k|v]
  u16* rmean = (u16*)alloc(32 * 512 * 2);
  u16* gi = (u16*)alloc(32 * 1024 * 2);
  u16* membf = (u16*)alloc((size_t)41280 * 512 * 2);
  u16* qbuf = (u16*)alloc((size_t)41280 * 512 * 2);
  u16* obuf = (u16*)alloc((size_t)41280 * 512 * 2);   // + gmbuf = contiguous 84.5MB region
  u16* gmbuf = (u16*)alloc((size_t)41280 * 512 * 2);
  u16* nmbf = (u16*)alloc((size_t)41280 * 512 * 2);
  (void)gmbuf;
  u16* kvbuf = obuf;    // [41280][1024] spans obuf+gmbuf (both free at that point)
  float* pacc = (float*)(void*)qbuf;  // 33.5MB (qbuf dead after gemm_gates)
  float* pml = (float*)((char*)(void*)qbuf + (size_t)4 * 32768 * 64 * 4);

  detect_kernel<<<1, 64, 0, stream>>>((const u16*)d_in[0], flag);
  {
    CvtArgs ca;
    for (int i = 0; i < 23; ++i) {
      int ii = (i < n_in) ? i : (n_in - 1);
      ca.src[i] = d_in[ii];
      ca.aoff[i] = (int)aoffs[ii];
      ca.n[i] = in_sizes[ii];
    }
    ca.total = (int)total;
    convert_fused<<<(unsigned)((total / 4 + 255) / 256), 256, 0, stream>>>(ca, arena, flag);
  }
  biascat_kernel<<<1, 512, 0, stream>>>(c_bq, c_bk, c_bv, bqkv, bkv);

  transpose_kernel<<<dim3(16, 16), 256, 0, stream>>>(c_Wq, WqkvT, 512, 512);
  transpose_kernel<<<dim3(16, 16), 256, 0, stream>>>(c_Wk, WqkvT + (size_t)512 * 512, 512, 512);
  transpose_kernel<<<dim3(16, 16), 256, 0, stream>>>(c_Wv, WqkvT + (size_t)1024 * 512, 512, 512);
  transpose_kernel<<<dim3(16, 16), 256, 0, stream>>>(c_Wm, WmT, 512, 512);
  transpose_kernel<<<dim3(16, 16), 256, 0, stream>>>(c_Wp, WpT, 512, 512);
  transpose_kernel<<<dim3(32, 16), 256, 0, stream>>>(c_Wig, WigT, 512, 1024);
  transpose_kernel<<<dim3(32, 16), 256, 0, stream>>>(c_Wmg, WmgT, 512, 1024);

  gemm_bt<0><<<dim3(32 * 4), 256, 0, stream>>>(c_ipts, WpT, c_bp, inp, 4096, 512, 4);
  // fused QKV projection of inp: [4096][1536] = inp @ [Wq|Wk|Wv]
  gemm_bt<0><<<dim3(32 * 12), 256, 0, stream>>>(inp, WqkvT, bqkv, qkvbuf, 4096, 1536, 12);

  redmean_kernel<<<dim3(32, 2), 256, 0, stream>>>(inp, c_repw, rmean);
  gemm_bt<0><<<dim3(1 * 8), 256, 0, stream>>>(rmean, WigT, c_big, gi, 32, 1024, 8);

  const u16* memsrc = c_mem;
  for (int it = 0; it < 4; ++it) {
    gemm_bt<0><<<dim3(323 * 4), 256, 0, stream>>>(memsrc, WqkvT, c_bq, qbuf, 41280, 512, 4);
    attn1_mfma<<<dim3(11, 256), 256, 0, stream>>>(qbuf, qkvbuf + 512, qkvbuf + 1024, obuf, 1536);
    ln_kernel<<<dim3(10320), 256, 0, stream>>>(memsrc, obuf, membf, c_g1, c_b1);
    gemm_bt<1><<<dim3(323 * 4), 256, 0, stream>>>(membf, WmT, c_bm, qbuf, 41280, 512, 4);
    gemm_bt<1><<<dim3(323 * 4), 256, 0, stream>>>(qbuf, WmT, c_bm, obuf, 41280, 512, 4);
    ln_kernel<<<dim3(10320), 256, 0, stream>>>(membf, obuf, membf, c_g2, c_b2);
    memsrc = membf;
  }

  tanhmem_kernel<<<dim3(2641920 / 256), 256, 0, stream>>>(c_mem, qbuf, 2641920);
  // fused gate GEMM + gates: reads tanh(mem), Wmg(both halves), membf, c_mem;
  // writes next_memory (nmbf) + d_out directly. No gm round-trip.
  gemm_gates<<<dim3(323 * 8), 256, 0, stream>>>(qbuf, WmgT, c_bmg, gi, membf, c_mem,
                                                c_ib, c_fb, nmbf, d_out, flag, 41280);

  // fused K/V projection of next_memory: [41280][1024] = nmbf @ [Wk|Wv]
  gemm_bt<0><<<dim3(323 * 8), 256, 0, stream>>>(nmbf, WqkvT + (size_t)512 * 512, bkv,
                                                kvbuf, 41280, 1024, 8);
  attn2_mfma<<<dim3(256, 4), 256, 0, stream>>>(qkvbuf, kvbuf, kvbuf + 512, pacc, pml,
                                               1536, 1024);
  attn2_merge<<<dim3(32768), 64, 0, stream>>>(pacc, pml, d_out, flag);
}

// Round 9
// 1193.585 us; speedup vs baseline: 1.4786x; 1.3131x over previous
//
#include <hip/hip_runtime.h>
#include <stdint.h>

typedef uint16_t u16;
typedef uint32_t u32;

#define DEVI __device__ __forceinline__

DEVI float b2f(u16 u) { return __uint_as_float(((u32)u) << 16); }
DEVI float blo(u32 u) { return __uint_as_float(u << 16); }
DEVI float bhi(u32 u) { return __uint_as_float(u & 0xffff0000u); }
DEVI u16 f2b(float f) {
  u32 x = __float_as_uint(f);
  return (u16)((x + 0x7fffu + ((x >> 16) & 1u)) >> 16);
}
DEVI u32 pack2(float a, float b) { return (u32)f2b(a) | ((u32)f2b(b) << 16); }
DEVI float sigm(float x) { return 1.f / (1.f + __expf(-x)); }
// fast tanh: exact at +-inf, ~1e-6 rel error (bf16 output rounds at 2^-8)
DEVI float ftanh(float x) { return 1.f - 2.f / (1.f + __expf(2.f * x)); }

typedef __bf16 bf16x8 __attribute__((ext_vector_type(8)));
typedef float f32x4 __attribute__((ext_vector_type(4)));

#define MFMA16(a, b, c) __builtin_amdgcn_mfma_f32_16x16x32_bf16(a, b, c, 0, 0, 0)

DEVI void gll16(const void* g, void* l) {
  __builtin_amdgcn_global_load_lds((const __attribute__((address_space(1))) void*)g,
                                   (__attribute__((address_space(3))) void*)l, 16, 0, 0);
}

// monotonic total-order map for f32 bits
DEVI u32 fmono(float s) {
  u32 x = __float_as_uint(s);
  return x ^ (((u32)((int)x >> 31)) | 0x80000000u);
}

// descending compare-exchange (max to lower index)
DEVI void ced(u32& a, u32& b) {
  u32 hi = max(a, b), lo = min(a, b);
  a = hi; b = lo;
}
// Batcher odd-even merge sort, 8 elems, descending (19 CE)
DEVI void sort8_desc(u32* v) {
  ced(v[0], v[1]); ced(v[2], v[3]); ced(v[4], v[5]); ced(v[6], v[7]);
  ced(v[0], v[2]); ced(v[1], v[3]); ced(v[4], v[6]); ced(v[5], v[7]);
  ced(v[1], v[2]); ced(v[5], v[6]);
  ced(v[0], v[4]); ced(v[1], v[5]); ced(v[2], v[6]); ced(v[3], v[7]);
  ced(v[2], v[4]); ced(v[3], v[5]);
  ced(v[1], v[2]); ced(v[3], v[4]); ced(v[5], v[6]);
}
// bitonic 8-sequence -> descending sorted (12 CE)
DEVI void bitonic8_desc(u32* v) {
  ced(v[0], v[4]); ced(v[1], v[5]); ced(v[2], v[6]); ced(v[3], v[7]);
  ced(v[0], v[2]); ced(v[1], v[3]); ced(v[4], v[6]); ced(v[5], v[7]);
  ced(v[0], v[1]); ced(v[2], v[3]); ced(v[4], v[5]); ced(v[6], v[7]);
}
// a,b desc-sorted 8-lists -> a = top-8 of union, desc sorted
DEVI void merge_top8(u32* a, const u32* b) {
#pragma unroll
  for (int j = 0; j < 8; ++j) a[j] = max(a[j], b[7 - j]);
  bitonic8_desc(a);
}

// ---------------- input dtype detect: 0 = bf16, 1 = fp32 ----------------
__global__ void detect_kernel(const u16* __restrict__ x, int* __restrict__ flag) {
  if (threadIdx.x == 0 && blockIdx.x == 0) {
    int f = 0;
    for (int i = 0; i < 64; ++i) {
      u16 u = x[2 * i];  // low half if fp32
      int e = (u >> 7) & 0xFF;
      if (e > 131) f = 1;  // |val| >= 32 impossible for randn bf16
    }
    *flag = f;
  }
}

// ---------------- fused convert: all inputs -> bf16 arena, one dispatch ----------------
struct CvtArgs {
  const void* src[23];
  int aoff[23];
  int n[23];
  int total;
};

__global__ __launch_bounds__(256) void convert_fused(CvtArgs a, u16* __restrict__ arena,
                                                     const int* __restrict__ flag) {
  int e4 = (blockIdx.x * 256 + threadIdx.x) * 4;
  if (e4 >= a.total) return;
  const char* sp = (const char*)a.src[0];
  int rel = e4, cnt = a.n[0];
#pragma unroll
  for (int j = 1; j < 23; ++j)
    if (e4 >= a.aoff[j]) { sp = (const char*)a.src[j]; rel = e4 - a.aoff[j]; cnt = a.n[j]; }
  const bool f32 = (*flag != 0);
  if (rel + 3 < cnt) {
    if (f32) {
      float4 v = *(const float4*)(sp + (size_t)rel * 4);
      uint2 o;
      o.x = pack2(v.x, v.y);
      o.y = pack2(v.z, v.w);
      *(uint2*)(arena + e4) = o;
    } else {
      *(uint2*)(arena + e4) = *(const uint2*)(sp + (size_t)rel * 2);
    }
  } else {
#pragma unroll
    for (int k = 0; k < 4; ++k) {
      u16 o = 0;
      if (rel + k < cnt)
        o = f32 ? f2b(((const float*)sp)[rel + k]) : ((const u16*)sp)[rel + k];
      arena[e4 + k] = o;
    }
  }
}

// ---------------- bias concat: bqkv=[bq|bk|bv], bkv=[bk|bv] ----------------
__global__ void biascat_kernel(const u16* __restrict__ bq, const u16* __restrict__ bk,
                               const u16* __restrict__ bv, u16* __restrict__ bqkv,
                               u16* __restrict__ bkv) {
  int t = threadIdx.x;  // 512
  bqkv[t] = bq[t];
  bqkv[512 + t] = bk[t];
  bqkv[1024 + t] = bv[t];
  bkv[t] = bk[t];
  bkv[512 + t] = bv[t];
}

// ---------------- GEMM: m97 pattern + XCD swizzle + coalesced epilogue + 2-PHASE PIPELINE --
// BK=32, double-buffered staging (2x16KB) aliased under the 34.8KB epilogue buffer ->
// occupancy 4 (NOT 5: unified VGPR+AGPR needs ~112 regs/lane; bound 5 => 102 => spill,
// measured R8: WRITE_SIZE 124->305MB scratch traffic). Per iteration: issue next tile's
// gll16 BEFORE ds_read+MFMA of current; trailing __syncthreads drains prefetch AFTER
// compute -> HBM latency hidden (T3 minimum 2-phase recipe).
template <int ACT>
__global__ __launch_bounds__(256, 4) void gemm_bt(
    const u16* __restrict__ A, const u16* __restrict__ Bt,
    const u16* __restrict__ bias, u16* __restrict__ Co, int Mtot, int Ntot, int nby) {
  __shared__ __align__(16) u16 smem[128 * 136];  // staging dbuf (32KB) / epilogue st (34.8KB)
  u16* const aB0 = smem;
  u16* const aB1 = smem + 4096;
  u16* const bB0 = smem + 8192;
  u16* const bB1 = smem + 12288;
  const int tid = threadIdx.x;
  const int lane = tid & 63;
  const int w = tid >> 6;
  const int quad = lane >> 4;
  const int l15 = lane & 15;

  const int nwg = gridDim.x;
  const int orig = blockIdx.x;
  const int xcd = orig & 7, sq = orig >> 3;
  const int qd = nwg >> 3, rm = nwg & 7;
  const int wg = (xcd < rm ? xcd * (qd + 1) : rm * (qd + 1) + (xcd - rm) * qd) + sq;
  const int m0 = (wg / nby) * 128;
  const int n0 = (wg % nby) * 128;

  const int wm = (w & 1) << 6;
  const int wn = (w >> 1) << 6;

  f32x4 acc[4][4] = {};

  const u16* ga[2];
  const u16* gb[2];
#pragma unroll
  for (int q = 0; q < 2; ++q) {
    int j = q * 256 + tid;
    int r = j >> 2, s = j & 3;
    int c = (s ^ ((r >> 1) & 3)) * 8;
    int ra = m0 + r;
    if (ra >= Mtot) ra = Mtot - 1;
    ga[q] = A + (size_t)ra * 512 + c;
    gb[q] = Bt + (size_t)(n0 + r) * 512 + c;
  }

  auto stage = [&](int p, int ko) {
    u16* ab = p ? aB1 : aB0;
    u16* bb = p ? bB1 : bB0;
#pragma unroll
    for (int q = 0; q < 2; ++q) {
      int j = q * 256 + tid;
      gll16(ga[q] + ko * 32, ab + j * 8);
      gll16(gb[q] + ko * 32, bb + j * 8);
    }
  };

  stage(0, 0);
  __syncthreads();
  int cur = 0;
  for (int ko = 0; ko < 16; ++ko) {
    if (ko < 15) stage(cur ^ 1, ko + 1);
    u16* ab = cur ? aB1 : aB0;
    u16* bb = cur ? bB1 : bB0;
    bf16x8 af[4], bfr[4];
#pragma unroll
    for (int i = 0; i < 4; ++i) {
      int r = wm + i * 16 + l15;
      af[i] = *(const bf16x8*)(ab + (((r << 2) | (quad ^ ((r >> 1) & 3)))) * 8);
      int rn = wn + i * 16 + l15;
      bfr[i] = *(const bf16x8*)(bb + (((rn << 2) | (quad ^ ((rn >> 1) & 3)))) * 8);
    }
#pragma unroll
    for (int i = 0; i < 4; ++i)
#pragma unroll
      for (int jn = 0; jn < 4; ++jn)
        acc[i][jn] = MFMA16(af[i], bfr[jn], acc[i][jn]);
    __syncthreads();
    cur ^= 1;
  }

  // epilogue: bias/act -> bf16 into LDS st[128][136], then coalesced 16B stores
  u16* st = smem;
#pragma unroll
  for (int jn = 0; jn < 4; ++jn) {
    int coll = wn + jn * 16 + l15;
    float bv = b2f(bias[n0 + coll]);
#pragma unroll
    for (int i = 0; i < 4; ++i) {
      int rowb = wm + i * 16 + quad * 4;
#pragma unroll
      for (int rr = 0; rr < 4; ++rr) {
        float vv = acc[i][jn][rr] + bv;
        if (ACT) vv = fmaxf(vv, 0.f);
        st[(rowb + rr) * 136 + coll] = f2b(vv);
      }
    }
  }
  __syncthreads();
#pragma unroll
  for (int t = 0; t < 8; ++t) {
    int idx = (t * 256 + tid) * 8;  // u16 units within 128x128 tile
    int r = idx >> 7;
    int c = idx & 127;
    int row = m0 + r;
    if (row < Mtot) {
      uint4 v = *(const uint4*)(st + r * 136 + c);
      *(uint4*)(Co + (size_t)row * Ntot + n0 + c) = v;
    }
  }
}

// ---------------- gate GEMM + gates fused (2-phase pipelined) ----------------
__global__ __launch_bounds__(256, 4) void gemm_gates(
    const u16* __restrict__ A, const u16* __restrict__ WmgTp,
    const u16* __restrict__ bmg, const u16* __restrict__ gi,
    const u16* __restrict__ memfin, const u16* __restrict__ mem_in,
    const u16* __restrict__ ibp, const u16* __restrict__ fbp,
    u16* __restrict__ nmbf, void* __restrict__ outp, const int* __restrict__ flag,
    int Mtot) {
  __shared__ __align__(16) u16 smem[128 * 136];
  u16* const aB0 = smem;
  u16* const aB1 = smem + 4096;
  u16* const bB0 = smem + 8192;
  u16* const bB1 = smem + 12288;
  const int tid = threadIdx.x;
  const int lane = tid & 63;
  const int w = tid >> 6;
  const int quad = lane >> 4;
  const int l15 = lane & 15;

  const int nwg = gridDim.x;
  const int orig = blockIdx.x;
  const int xcd = orig & 7, sq = orig >> 3;
  const int qd = nwg >> 3, rm = nwg & 7;
  const int wg = (xcd < rm ? xcd * (qd + 1) : rm * (qd + 1) + (xcd - rm) * qd) + sq;
  const int m0 = (wg >> 3) * 128;    // nby = 8
  const int n0h = (wg & 7) * 64;     // col offset within [0,512)

  const int wm = (w & 1) << 6;
  const int wn = (w >> 1) << 6;

  f32x4 acc[4][4] = {};

  const u16* ga[2];
  const u16* gb[2];
#pragma unroll
  for (int q = 0; q < 2; ++q) {
    int j = q * 256 + tid;
    int r = j >> 2, s = j & 3;
    int c = (s ^ ((r >> 1) & 3)) * 8;
    int ra = m0 + r;
    if (ra >= Mtot) ra = Mtot - 1;
    ga[q] = A + (size_t)ra * 512 + c;
    int br = (r < 64) ? (n0h + r) : (512 + n0h + r - 64);  // ig half | fg half
    gb[q] = WmgTp + (size_t)br * 512 + c;
  }

  auto stage = [&](int p, int ko) {
    u16* ab = p ? aB1 : aB0;
    u16* bb = p ? bB1 : bB0;
#pragma unroll
    for (int q = 0; q < 2; ++q) {
      int j = q * 256 + tid;
      gll16(ga[q] + ko * 32, ab + j * 8);
      gll16(gb[q] + ko * 32, bb + j * 8);
    }
  };

  stage(0, 0);
  __syncthreads();
  int cur = 0;
  for (int ko = 0; ko < 16; ++ko) {
    if (ko < 15) stage(cur ^ 1, ko + 1);
    u16* ab = cur ? aB1 : aB0;
    u16* bb = cur ? bB1 : bB0;
    bf16x8 af[4], bfr[4];
#pragma unroll
    for (int i = 0; i < 4; ++i) {
      int r = wm + i * 16 + l15;
      af[i] = *(const bf16x8*)(ab + (((r << 2) | (quad ^ ((r >> 1) & 3)))) * 8);
      int rn = wn + i * 16 + l15;
      bfr[i] = *(const bf16x8*)(bb + (((rn << 2) | (quad ^ ((rn >> 1) & 3)))) * 8);
    }
#pragma unroll
    for (int i = 0; i < 4; ++i)
#pragma unroll
      for (int jn = 0; jn < 4; ++jn)
        acc[i][jn] = MFMA16(af[i], bfr[jn], acc[i][jn]);
    __syncthreads();
    cur ^= 1;
  }

  // stage gm (bf16, with bmg bias) into LDS: cols 0..63 = ig, 64..127 = fg
  u16* st = smem;
#pragma unroll
  for (int jn = 0; jn < 4; ++jn) {
    int coll = wn + jn * 16 + l15;
    int bcol = (coll < 64) ? (n0h + coll) : (512 + n0h + coll - 64);
    float bv = b2f(bmg[bcol]);
#pragma unroll
    for (int i = 0; i < 4; ++i) {
      int rowb = wm + i * 16 + quad * 4;
#pragma unroll
      for (int rr = 0; rr < 4; ++rr)
        st[(rowb + rr) * 136 + coll] = f2b(acc[i][jn][rr] + bv);
    }
  }
  __syncthreads();

  const float ib = b2f(ibp[0]);
  const float fb = b2f(fbp[0]);
  const bool of32 = (*flag != 0);
#pragma unroll
  for (int t = 0; t < 4; ++t) {
    int chunk = t * 256 + tid;        // 1024 chunks of 8 elems = 128 rows x 64 cols
    int rl = chunk >> 3;
    int c8 = (chunk & 7) * 8;
    int row = m0 + rl;
    if (row >= Mtot) continue;
    int b = row / 1290;
    size_t gidx = (size_t)row * 512 + n0h + c8;
    uint4 uig = *(const uint4*)(st + rl * 136 + c8);
    uint4 ufg = *(const uint4*)(st + rl * 136 + 64 + c8);
    uint4 ugi = *(const uint4*)(gi + b * 1024 + n0h + c8);
    uint4 ugf = *(const uint4*)(gi + b * 1024 + 512 + n0h + c8);
    uint4 umf = *(const uint4*)(memfin + gidx);
    uint4 umi = *(const uint4*)(mem_in + gidx);
    const u32* pig = (const u32*)&uig;
    const u32* pfg = (const u32*)&ufg;
    const u32* pgi = (const u32*)&ugi;
    const u32* pgf = (const u32*)&ugf;
    const u32* pmf = (const u32*)&umf;
    const u32* pmi = (const u32*)&umi;
    float v[8];
#pragma unroll
    for (int k = 0; k < 4; ++k) {
      float ig0 = sigm(blo(pig[k]) + blo(pgi[k]) + ib);
      float ig1 = sigm(bhi(pig[k]) + bhi(pgi[k]) + ib);
      float fg0 = sigm(blo(pfg[k]) + blo(pgf[k]) + fb);
      float fg1 = sigm(bhi(pfg[k]) + bhi(pgf[k]) + fb);
      v[2 * k] = ig0 * ftanh(blo(pmf[k])) + fg0 * blo(pmi[k]);
      v[2 * k + 1] = ig1 * ftanh(bhi(pmf[k])) + fg1 * bhi(pmi[k]);
    }
    uint4 o;
    u32* po = (u32*)&o;
#pragma unroll
    for (int k = 0; k < 4; ++k) po[k] = pack2(v[2 * k], v[2 * k + 1]);
    *(uint4*)(nmbf + gidx) = o;
    if (of32) {
      float4 f0, f1;
      f0.x = v[0]; f0.y = v[1]; f0.z = v[2]; f0.w = v[3];
      f1.x = v[4]; f1.y = v[5]; f1.z = v[6]; f1.w = v[7];
      *(float4*)((float*)outp + gidx) = f0;
      *(float4*)((float*)outp + gidx + 4) = f1;
    } else {
      *(uint4*)((u16*)outp + gidx) = o;
    }
  }
}

// ---------------- weight transpose ----------------
__global__ __launch_bounds__(256) void transpose_kernel(const u16* __restrict__ in,
                                                        u16* __restrict__ outb, int K, int N) {
  __shared__ u16 tile[32][33];
  const int tx = threadIdx.x & 31, ty = threadIdx.x >> 5;
  const int bx = blockIdx.x * 32;
  const int by = blockIdx.y * 32;
#pragma unroll
  for (int i = 0; i < 32; i += 8) tile[ty + i][tx] = in[(size_t)(by + ty + i) * N + bx + tx];
  __syncthreads();
#pragma unroll
  for (int i = 0; i < 32; i += 8) outb[(size_t)(bx + ty + i) * K + by + tx] = tile[tx][ty + i];
}

// ---------------- tanh(memory) ----------------
__global__ void tanhmem_kernel(const u16* __restrict__ mi, u16* __restrict__ th, int n8) {
  int i = blockIdx.x * 256 + threadIdx.x;
  if (i >= n8) return;
  uint4 u = ((const uint4*)mi)[i];
  uint4 t;
  t.x = pack2(ftanh(blo(u.x)), ftanh(bhi(u.x)));
  t.y = pack2(ftanh(blo(u.y)), ftanh(bhi(u.y)));
  t.z = pack2(ftanh(blo(u.z)), ftanh(bhi(u.z)));
  t.w = pack2(ftanh(blo(u.w)), ftanh(bhi(u.w)));
  ((uint4*)th)[i] = t;
}

// ---------------- rmean ----------------
__global__ void redmean_kernel(const u16* __restrict__ inp, const u16* __restrict__ repw,
                               u16* __restrict__ outb) {
  const int b = blockIdx.x;
  const int c = blockIdx.y * 256 + threadIdx.x;
  const float rw = b2f(repw[c]);
  float s = 0.f;
  for (int t = 0; t < 128; ++t)
    s += fmaxf(rw * b2f(inp[(size_t)(b * 128 + t) * 512 + c]), 0.f);
  outb[b * 512 + c] = f2b(s * (1.f / 128.f));
}

// ---------------- LayerNorm (4 rows/block, 1 wave per row) ----------------
__global__ __launch_bounds__(256) void ln_kernel(const u16* __restrict__ src,
                                                 const u16* __restrict__ addb,
                                                 u16* __restrict__ dst,
                                                 const u16* __restrict__ g,
                                                 const u16* __restrict__ bb) {
  const int row = blockIdx.x * 4 + (threadIdx.x >> 6);
  const int lane = threadIdx.x & 63;
  const u16* srow = src + (size_t)row * 512;
  const u16* arow = addb + (size_t)row * 512;
  float x[8];
  float s = 0.f;
#pragma unroll
  for (int i = 0; i < 8; ++i) {
    int c = lane + i * 64;
    x[i] = b2f(srow[c]) + b2f(arow[c]);
    s += x[i];
  }
#pragma unroll
  for (int off = 32; off > 0; off >>= 1) s += __shfl_xor(s, off, 64);
  const float mu = s * (1.f / 512.f);
  float v = 0.f;
#pragma unroll
  for (int i = 0; i < 8; ++i) {
    float d = x[i] - mu;
    v = fmaf(d, d, v);
  }
#pragma unroll
  for (int off = 32; off > 0; off >>= 1) v += __shfl_xor(v, off, 64);
  const float rstd = rsqrtf(v * (1.f / 512.f) + 1e-5f);
  u16* orow = dst + (size_t)row * 512;
#pragma unroll
  for (int i = 0; i < 8; ++i) {
    int c = lane + i * 64;
    orow[c] = f2b(fmaf((x[i] - mu) * rstd, b2f(g[c]), b2f(bb[c])));
  }
}

// ---------------- attention 1 (MFMA): 1290 q (mem), 128 k (inp), top-8 mask ----------------
__global__ __launch_bounds__(256, 3) void attn1_mfma(const u16* __restrict__ q,
                                                     const u16* __restrict__ kb,
                                                     const u16* __restrict__ vb,
                                                     u16* __restrict__ o, int ldkv) {
  __shared__ __align__(16) u16 Pl[128 * 136];  // masked P [q][k]; rows 0..60 alias Kl
  __shared__ __align__(16) u16 VT[64 * 136];   // V^T [d][k]
  __shared__ float lbuf[128];                  // 1/l per local query
  u16* Kl = Pl;                                // phase-1 alias: swizzled K [key][dim]

  const int tid = threadIdx.x;
  const int lane = tid & 63;
  const int w = tid >> 6;
  const int quad = lane >> 4;
  const int l15 = lane & 15;
  const int qb = blockIdx.x;
  const int bh = blockIdx.y;
  const int b = bh >> 3, h = bh & 7;

  // stage K swizzled (gll16) into Kl
#pragma unroll
  for (int qq = 0; qq < 4; ++qq) {
    int j = qq * 256 + tid;
    int r = j >> 3, s = j & 7;
    gll16(kb + (size_t)(b * 128 + r) * ldkv + h * 64 + (s ^ (r & 7)) * 8, Kl + j * 8);
  }
  // stage V transposed: per wave, 64 consecutive keys per d-row write (2-way banks, free)
#pragma unroll
  for (int p = 0; p < 4; ++p) {
    int key = (tid & 63) + 64 * (p & 1);
    int dc = w + 4 * (p >> 1);
    uint4 u = *(const uint4*)(vb + (size_t)(b * 128 + key) * ldkv + h * 64 + dc * 8);
    u16 tmp[8];
    *(uint4*)tmp = u;
#pragma unroll
    for (int jj = 0; jj < 8; ++jj) VT[(dc * 8 + jj) * 136 + key] = tmp[jj];
  }

  // Q fragments (B-operand): col = query, quad picks dim-chunk
  bf16x8 bq[2][2];
  {
    int ra = min(qb * 128 + w * 32 + l15, 1289);
    int rb_ = min(qb * 128 + w * 32 + 16 + l15, 1289);
    const u16* qa = q + (size_t)(b * 1290 + ra) * 512 + h * 64 + quad * 8;
    const u16* qc = q + (size_t)(b * 1290 + rb_) * 512 + h * 64 + quad * 8;
    bq[0][0] = *(const bf16x8*)(qa);
    bq[0][1] = *(const bf16x8*)(qa + 32);
    bq[1][0] = *(const bf16x8*)(qc);
    bq[1][1] = *(const bf16x8*)(qc + 32);
  }
  __syncthreads();

  // S^T = K.Q^T : thread holds query (w*32+i*16+l15), k = jn*16+quad*4+rr
  f32x4 sa[2][8] = {};
#pragma unroll
  for (int ks = 0; ks < 2; ++ks) {
#pragma unroll
    for (int jn = 0; jn < 8; ++jn) {
      int n = jn * 16 + l15;
      int cch = ks * 4 + quad;
      bf16x8 ak = *(const bf16x8*)(Kl + (n * 8 + (cch ^ (n & 7))) * 8);
      sa[0][jn] = MFMA16(ak, bq[0][ks], sa[0][jn]);
      sa[1][jn] = MFMA16(ak, bq[1][ks], sa[1][jn]);
    }
  }
  __syncthreads();  // all Kl reads done before P overwrites the aliased region

  const u32 ibase = 127u - (u32)(quad * 4);
#pragma unroll
  for (int i = 0; i < 2; ++i) {
    const int qi = w * 32 + i * 16 + l15;
    // build packed keys (scale scores in place; sa keeps f32 for the exp pass)
    u32 g[4][8];
#pragma unroll
    for (int jn = 0; jn < 8; ++jn)
#pragma unroll
      for (int rr = 0; rr < 4; ++rr) {
        float s = sa[i][jn][rr] * 0.125f;
        sa[i][jn][rr] = s;
        g[jn >> 1][(jn & 1) * 4 + rr] =
            (fmono(s) & 0xFFFFFF80u) | (ibase - (u32)(jn * 16 + rr));
      }
    // local top-8: 4x sort8 + merge tree
    sort8_desc(g[0]); sort8_desc(g[1]); sort8_desc(g[2]); sort8_desc(g[3]);
    merge_top8(g[0], g[1]);
    merge_top8(g[2], g[3]);
    merge_top8(g[0], g[2]);
    u32* tv = g[0];
    // merge sorted top-8 lists across quads (xor 16, then 32)
#pragma unroll
    for (int off = 16; off < 64; off <<= 1) {
      u32 pv[8];
#pragma unroll
      for (int j = 0; j < 8; ++j) pv[j] = (u32)__shfl_xor((int)tv[7 - j], off, 64);
#pragma unroll
      for (int j = 0; j < 8; ++j) tv[j] = max(tv[j], pv[j]);
      bitonic8_desc(tv);
    }
    const u32 t8 = tv[7];  // 8th largest packed key; membership = (key >= t8)
    // decode running max (25-bit truncated; <= true max, safe for exp)
    u32 mb = tv[0] & 0xFFFFFF80u;
    u32 xm = (mb & 0x80000000u) ? (mb ^ 0x80000000u) : ~mb;
    const float mx = __uint_as_float(xm);
    // single pass: denom over all 128 + masked unnormalized P write
    float lsum = 0.f;
#pragma unroll
    for (int jn = 0; jn < 8; ++jn) {
      u16 pr[4];
#pragma unroll
      for (int rr = 0; rr < 4; ++rr) {
        float s = sa[i][jn][rr];
        float e = __expf(s - mx);
        lsum += e;
        u32 kk = (fmono(s) & 0xFFFFFF80u) | (ibase - (u32)(jn * 16 + rr));
        pr[rr] = (kk >= t8) ? f2b(e) : (u16)0;
      }
      uint2 st;
      st.x = (u32)pr[0] | ((u32)pr[1] << 16);
      st.y = (u32)pr[2] | ((u32)pr[3] << 16);
      *(uint2*)(Pl + qi * 136 + jn * 16 + quad * 4) = st;
    }
    lsum += __shfl_xor(lsum, 16, 64);
    lsum += __shfl_xor(lsum, 32, 64);
    if (quad == 0) lbuf[qi] = 1.f / lsum;
  }
  __syncthreads();

  // O = P.V  (A = masked P rows, B = VT rows)
  f32x4 oa[2][4] = {};
#pragma unroll
  for (int kc = 0; kc < 4; ++kc) {
    bf16x8 ap[2];
#pragma unroll
    for (int i = 0; i < 2; ++i)
      ap[i] = *(const bf16x8*)(Pl + (w * 32 + i * 16 + l15) * 136 + kc * 32 + quad * 8);
#pragma unroll
    for (int jd = 0; jd < 4; ++jd) {
      bf16x8 bv_ = *(const bf16x8*)(VT + (jd * 16 + l15) * 136 + kc * 32 + quad * 8);
      oa[0][jd] = MFMA16(ap[0], bv_, oa[0][jd]);
      oa[1][jd] = MFMA16(ap[1], bv_, oa[1][jd]);
    }
  }

  // epilogue: scale rows by 1/l, write bf16
#pragma unroll
  for (int i = 0; i < 2; ++i) {
    int rowl = w * 32 + i * 16 + quad * 4;
#pragma unroll
    for (int rr = 0; rr < 4; ++rr) {
      int qg = qb * 128 + rowl + rr;
      if (qg < 1290) {
        float il = lbuf[rowl + rr];
        u16* orow = o + (size_t)(b * 1290 + qg) * 512 + h * 64;
#pragma unroll
        for (int jd = 0; jd < 4; ++jd) orow[jd * 16 + l15] = f2b(oa[i][jd][rr] * il);
      }
    }
  }
}

// ---------------- attention 2 (MFMA flash): 128 q (inp), 1290 k (next_memory) ----------------
__global__ __launch_bounds__(256, 2) void attn2_mfma(const u16* __restrict__ q2,
                                                     const u16* __restrict__ k2,
                                                     const u16* __restrict__ v2,
                                                     float* __restrict__ pacc,
                                                     float* __restrict__ pml,
                                                     int ldq, int ldkv) {
  __shared__ __align__(16) u16 Kl[64 * 64];      // swizzled [key][dim]
  __shared__ __align__(16) u16 VT[64 * 72];      // [dim][key], stride 72
  __shared__ __align__(16) u16 Pl[4 * 32 * 72];  // per-wave P [32q][64k]
  const int tid = threadIdx.x;
  const int lane = tid & 63;
  const int w = tid >> 6;
  const int quad = lane >> 4;
  const int l15 = lane & 15;
  const int bh = blockIdx.x;
  const int b = bh >> 3, h = bh & 7;
  const int part = blockIdx.y;
  const int kstart = (part * 1290) >> 2;
  const int kend = ((part + 1) * 1290) >> 2;

  bf16x8 aq[2][2];
  {
    int r0 = b * 128 + w * 32 + l15;
    const u16* qa = q2 + (size_t)r0 * ldq + h * 64 + quad * 8;
    aq[0][0] = *(const bf16x8*)(qa);
    aq[0][1] = *(const bf16x8*)(qa + 32);
    aq[1][0] = *(const bf16x8*)(qa + (size_t)16 * ldq);
    aq[1][1] = *(const bf16x8*)(qa + (size_t)16 * ldq + 32);
  }

  f32x4 oa[2][4] = {};
  float m_[2][4], l_[2][4];
#pragma unroll
  for (int i = 0; i < 2; ++i)
#pragma unroll
    for (int r = 0; r < 4; ++r) { m_[i][r] = -1e30f; l_[i][r] = 0.f; }

  const int nk = kend - kstart;
  for (int kt = 0; kt < nk; kt += 64) {
    __syncthreads();
    // stage K swizzled (gll16)
#pragma unroll
    for (int qq = 0; qq < 2; ++qq) {
      int j = qq * 256 + tid;
      int r = j >> 3, s = j & 7;
      int kg = kstart + kt + r;
      if (kg >= kend) kg = kend - 1;
      gll16(k2 + (size_t)(b * 1290 + kg) * ldkv + h * 64 + (s ^ (r & 7)) * 8, Kl + j * 8);
    }
    // stage V transposed: lane r = key, dc = dim chunk (write banks: const + r/2 -> 2-way free)
    {
      int r = tid & 63;
      int kg = kstart + kt + r;
      if (kg >= kend) kg = kend - 1;
      const u16* vrow = v2 + (size_t)(b * 1290 + kg) * ldkv + h * 64;
#pragma unroll
      for (int p = 0; p < 2; ++p) {
        int dc = (tid >> 6) + p * 4;
        uint4 u = *(const uint4*)(vrow + dc * 8);
        u16 tmp[8];
        *(uint4*)tmp = u;
#pragma unroll
        for (int jj = 0; jj < 8; ++jj) VT[(dc * 8 + jj) * 72 + r] = tmp[jj];
      }
    }
    __syncthreads();

    // S = Q.K^T
    f32x4 sa[2][4] = {};
#pragma unroll
    for (int ks = 0; ks < 2; ++ks) {
#pragma unroll
      for (int jn = 0; jn < 4; ++jn) {
        int n = jn * 16 + l15;
        int cch = ks * 4 + quad;
        bf16x8 bk = *(const bf16x8*)(Kl + (n * 8 + (cch ^ (n & 7))) * 8);
        sa[0][jn] = MFMA16(aq[0][ks], bk, sa[0][jn]);
        sa[1][jn] = MFMA16(aq[1][ks], bk, sa[1][jn]);
      }
    }

    // online softmax (C-layout: col=l15 is key, row=quad*4+r is query) + P to LDS
    u16* pw = Pl + w * (32 * 72);
#pragma unroll
    for (int i = 0; i < 2; ++i) {
      float rmax[4] = {-1e30f, -1e30f, -1e30f, -1e30f};
#pragma unroll
      for (int jn = 0; jn < 4; ++jn) {
        int kg = kstart + kt + jn * 16 + l15;
        bool val = kg < kend;
#pragma unroll
        for (int r = 0; r < 4; ++r) {
          float s = sa[i][jn][r] * 0.125f;
          s = val ? s : -1e30f;
          sa[i][jn][r] = s;
          rmax[r] = fmaxf(rmax[r], s);
        }
      }
#pragma unroll
      for (int off = 1; off < 16; off <<= 1)
#pragma unroll
        for (int r = 0; r < 4; ++r) rmax[r] = fmaxf(rmax[r], __shfl_xor(rmax[r], off, 64));
      float alpha[4];
#pragma unroll
      for (int r = 0; r < 4; ++r) {
        float mn = fmaxf(m_[i][r], rmax[r]);
        alpha[r] = __expf(m_[i][r] - mn);
        m_[i][r] = mn;
      }
      float lsum[4] = {0.f, 0.f, 0.f, 0.f};
#pragma unroll
      for (int jn = 0; jn < 4; ++jn)
#pragma unroll
        for (int r = 0; r < 4; ++r) {
          float p = __expf(sa[i][jn][r] - m_[i][r]);
          sa[i][jn][r] = p;
          lsum[r] += p;
        }
#pragma unroll
      for (int off = 1; off < 16; off <<= 1)
#pragma unroll
        for (int r = 0; r < 4; ++r) lsum[r] += __shfl_xor(lsum[r], off, 64);
#pragma unroll
      for (int r = 0; r < 4; ++r) l_[i][r] = l_[i][r] * alpha[r] + lsum[r];
#pragma unroll
      for (int jd = 0; jd < 4; ++jd)
#pragma unroll
        for (int r = 0; r < 4; ++r) oa[i][jd][r] *= alpha[r];
#pragma unroll
      for (int jn = 0; jn < 4; ++jn) {
        int col = jn * 16 + l15;
#pragma unroll
        for (int r = 0; r < 4; ++r)
          pw[(i * 16 + quad * 4 + r) * 72 + col] = f2b(sa[i][jn][r]);
      }
    }

    // O += P.V   (A = P from per-wave LDS, B = VT)
#pragma unroll
    for (int ks = 0; ks < 2; ++ks) {
      bf16x8 ap[2];
#pragma unroll
      for (int i = 0; i < 2; ++i)
        ap[i] = *(const bf16x8*)(pw + (i * 16 + l15) * 72 + ks * 32 + quad * 8);
#pragma unroll
      for (int jd = 0; jd < 4; ++jd) {
        bf16x8 bv_ = *(const bf16x8*)(VT + (jd * 16 + l15) * 72 + ks * 32 + quad * 8);
        oa[0][jd] = MFMA16(ap[0], bv_, oa[0][jd]);
        oa[1][jd] = MFMA16(ap[1], bv_, oa[1][jd]);
      }
    }
  }

  // store partials (C-layout scatter)
  float* pa = pacc + (size_t)(part * 256 + bh) * 128 * 64;
#pragma unroll
  for (int i = 0; i < 2; ++i) {
    int row = w * 32 + i * 16 + quad * 4;
#pragma unroll
    for (int r = 0; r < 4; ++r)
#pragma unroll
      for (int jd = 0; jd < 4; ++jd)
        pa[(size_t)(row + r) * 64 + jd * 16 + l15] = oa[i][jd][r];
    if (l15 == 0) {
#pragma unroll
      for (int r = 0; r < 4; ++r) {
        size_t pi = (size_t)(part * 256 + bh) * 128 + row + r;
        pml[pi * 2 + 0] = m_[i][r];
        pml[pi * 2 + 1] = l_[i][r];
      }
    }
  }
}

__global__ __launch_bounds__(64) void attn2_merge(const float* __restrict__ pacc,
                                                  const float* __restrict__ pml,
                                                  void* __restrict__ outp,
                                                  const int* __restrict__ flag) {
  const int qi = blockIdx.x;  // bh*128 + t
  const int bh = qi >> 7, t = qi & 127;
  const int b = bh >> 3, h = bh & 7;
  const int lane = threadIdx.x;
  float mv[4], lv[4];
  float m0 = -1e30f;
#pragma unroll
  for (int i = 0; i < 4; ++i) {
    size_t pi = (size_t)(i * 256 + bh) * 128 + t;
    mv[i] = pml[pi * 2];
    lv[i] = pml[pi * 2 + 1];
    m0 = fmaxf(m0, mv[i]);
  }
  float L = 0.f, accd = 0.f;
#pragma unroll
  for (int i = 0; i < 4; ++i) {
    size_t pi = (size_t)(i * 256 + bh) * 128 + t;
    float e = __expf(mv[i] - m0);
    L += lv[i] * e;
    accd += pacc[pi * 64 + lane] * e;
  }
  float v = accd / L;
  size_t off = (size_t)41280 * 512 + ((size_t)(b * 128 + t) * 512 + h * 64 + lane);
  if (*flag) ((float*)outp)[off] = v; else ((u16*)outp)[off] = f2b(v);
}

extern "C" void kernel_launch(void* const* d_in, const int* in_sizes, int n_in,
                              void* d_out, int out_size, void* d_ws, size_t ws_size,
                              hipStream_t stream) {
  (void)out_size; (void)ws_size;
  char* ws = (char*)d_ws;
  size_t off = 0;
  auto alloc = [&](size_t bytes) {
    char* p = ws + off;
    off += (bytes + 255) & ~(size_t)255;
    return (void*)p;
  };

  int* flag = (int*)alloc(256);

  size_t aoffs[32];
  size_t total = 0;
  for (int i = 0; i < n_in; ++i) {
    aoffs[i] = total;
    total += ((size_t)in_sizes[i] + 127) & ~(size_t)127;
  }
  u16* arena = (u16*)alloc(total * 2);

  const u16* c_ipts = arena + aoffs[0];
  const u16* c_mem  = arena + aoffs[1];
  const u16* c_Wq = arena + aoffs[2];  const u16* c_bq = arena + aoffs[3];
  const u16* c_Wk = arena + aoffs[4];  const u16* c_bk = arena + aoffs[5];
  const u16* c_Wv = arena + aoffs[6];  const u16* c_bv = arena + aoffs[7];
  const u16* c_Wm = arena + aoffs[8];  const u16* c_bm = arena + aoffs[9];
  const u16* c_g1 = arena + aoffs[10]; const u16* c_b1 = arena + aoffs[11];
  const u16* c_g2 = arena + aoffs[12]; const u16* c_b2 = arena + aoffs[13];
  const u16* c_Wp = arena + aoffs[14]; const u16* c_bp = arena + aoffs[15];
  const u16* c_repw = arena + aoffs[16];
  const u16* c_Wig = arena + aoffs[17]; const u16* c_big = arena + aoffs[18];
  const u16* c_Wmg = arena + aoffs[19]; const u16* c_bmg = arena + aoffs[20];
  const u16* c_fb = arena + aoffs[21];
  const u16* c_ib = arena + aoffs[22];

  u16* WqkvT = (u16*)alloc((size_t)1536 * 512 * 2);  // rows: Wq^T | Wk^T | Wv^T
  u16* WmT = (u16*)alloc(512 * 512 * 2);
  u16* WpT = (u16*)alloc(512 * 512 * 2);
  u16* WigT = (u16*)alloc(512 * 1024 * 2);
  u16* WmgT = (u16*)alloc(512 * 1024 * 2);
  u16* bqkv = (u16*)alloc(1536 * 2);
  u16* bkv = (u16*)alloc(1024 * 2);
  u16* inp = (u16*)alloc((size_t)4096 * 512 * 2);
  u16* qkvbuf = (u16*)alloc((size_t)4096 * 1536 * 2);  // [row][q|k|v]
  u16* rmean = (u16*)alloc(32 * 512 * 2);
  u16* gi = (u16*)alloc(32 * 1024 * 2);
  u16* membf = (u16*)alloc((size_t)41280 * 512 * 2);
  u16* qbuf = (u16*)alloc((size_t)41280 * 512 * 2);
  u16* obuf = (u16*)alloc((size_t)41280 * 512 * 2);   // + gmbuf = contiguous 84.5MB region
  u16* gmbuf = (u16*)alloc((size_t)41280 * 512 * 2);
  u16* nmbf = (u16*)alloc((size_t)41280 * 512 * 2);
  (void)gmbuf;
  u16* kvbuf = obuf;    // [41280][1024] spans obuf+gmbuf (both free at that point)
  float* pacc = (float*)(void*)qbuf;  // 33.5MB (qbuf dead after gemm_gates)
  float* pml = (float*)((char*)(void*)qbuf + (size_t)4 * 32768 * 64 * 4);

  detect_kernel<<<1, 64, 0, stream>>>((const u16*)d_in[0], flag);
  {
    CvtArgs ca;
    for (int i = 0; i < 23; ++i) {
      int ii = (i < n_in) ? i : (n_in - 1);
      ca.src[i] = d_in[ii];
      ca.aoff[i] = (int)aoffs[ii];
      ca.n[i] = in_sizes[ii];
    }
    ca.total = (int)total;
    convert_fused<<<(unsigned)((total / 4 + 255) / 256), 256, 0, stream>>>(ca, arena, flag);
  }
  biascat_kernel<<<1, 512, 0, stream>>>(c_bq, c_bk, c_bv, bqkv, bkv);

  transpose_kernel<<<dim3(16, 16), 256, 0, stream>>>(c_Wq, WqkvT, 512, 512);
  transpose_kernel<<<dim3(16, 16), 256, 0, stream>>>(c_Wk, WqkvT + (size_t)512 * 512, 512, 512);
  transpose_kernel<<<dim3(16, 16), 256, 0, stream>>>(c_Wv, WqkvT + (size_t)1024 * 512, 512, 512);
  transpose_kernel<<<dim3(16, 16), 256, 0, stream>>>(c_Wm, WmT, 512, 512);
  transpose_kernel<<<dim3(16, 16), 256, 0, stream>>>(c_Wp, WpT, 512, 512);
  transpose_kernel<<<dim3(32, 16), 256, 0, stream>>>(c_Wig, WigT, 512, 1024);
  transpose_kernel<<<dim3(32, 16), 256, 0, stream>>>(c_Wmg, WmgT, 512, 1024);

  gemm_bt<0><<<dim3(32 * 4), 256, 0, stream>>>(c_ipts, WpT, c_bp, inp, 4096, 512, 4);
  // fused QKV projection of inp: [4096][1536] = inp @ [Wq|Wk|Wv]
  gemm_bt<0><<<dim3(32 * 12), 256, 0, stream>>>(inp, WqkvT, bqkv, qkvbuf, 4096, 1536, 12);

  redmean_kernel<<<dim3(32, 2), 256, 0, stream>>>(inp, c_repw, rmean);
  gemm_bt<0><<<dim3(1 * 8), 256, 0, stream>>>(rmean, WigT, c_big, gi, 32, 1024, 8);

  const u16* memsrc = c_mem;
  for (int it = 0; it < 4; ++it) {
    gemm_bt<0><<<dim3(323 * 4), 256, 0, stream>>>(memsrc, WqkvT, c_bq, qbuf, 41280, 512, 4);
    attn1_mfma<<<dim3(11, 256), 256, 0, stream>>>(qbuf, qkvbuf + 512, qkvbuf + 1024, obuf, 1536);
    ln_kernel<<<dim3(10320), 256, 0, stream>>>(memsrc, obuf, membf, c_g1, c_b1);
    gemm_bt<1><<<dim3(323 * 4), 256, 0, stream>>>(membf, WmT, c_bm, qbuf, 41280, 512, 4);
    gemm_bt<1><<<dim3(323 * 4), 256, 0, stream>>>(qbuf, WmT, c_bm, obuf, 41280, 512, 4);
    ln_kernel<<<dim3(10320), 256, 0, stream>>>(membf, obuf, membf, c_g2, c_b2);
    memsrc = membf;
  }

  tanhmem_kernel<<<dim3(2641920 / 256), 256, 0, stream>>>(c_mem, qbuf, 2641920);
  // fused gate GEMM + gates: reads tanh(mem), Wmg(both halves), membf, c_mem;
  // writes next_memory (nmbf) + d_out directly. No gm round-trip.
  gemm_gates<<<dim3(323 * 8), 256, 0, stream>>>(qbuf, WmgT, c_bmg, gi, membf, c_mem,
                                                c_ib, c_fb, nmbf, d_out, flag, 41280);

  // fused K/V projection of next_memory: [41280][1024] = nmbf @ [Wk|Wv]
  gemm_bt<0><<<dim3(323 * 8), 256, 0, stream>>>(nmbf, WqkvT + (size_t)512 * 512, bkv,
                                                kvbuf, 41280, 1024, 8);
  attn2_mfma<<<dim3(256, 4), 256, 0, stream>>>(qkvbuf, kvbuf, kvbuf + 512, pacc, pml,
                                               1536, 1024);
  attn2_merge<<<dim3(32768), 64, 0, stream>>>(pacc, pml, d_out, flag);
}

// Round 10
// 1187.224 us; speedup vs baseline: 1.4866x; 1.0054x over previous
//
#include <hip/hip_runtime.h>
#include <stdint.h>

typedef uint16_t u16;
typedef uint32_t u32;

#define DEVI __device__ __forceinline__

DEVI float b2f(u16 u) { return __uint_as_float(((u32)u) << 16); }
DEVI float blo(u32 u) { return __uint_as_float(u << 16); }
DEVI float bhi(u32 u) { return __uint_as_float(u & 0xffff0000u); }
DEVI u16 f2b(float f) {
  u32 x = __float_as_uint(f);
  return (u16)((x + 0x7fffu + ((x >> 16) & 1u)) >> 16);
}
DEVI u32 pack2(float a, float b) { return (u32)f2b(a) | ((u32)f2b(b) << 16); }
DEVI float sigm(float x) { return 1.f / (1.f + __expf(-x)); }
// fast tanh: exact at +-inf, ~1e-6 rel error (bf16 output rounds at 2^-8)
DEVI float ftanh(float x) { return 1.f - 2.f / (1.f + __expf(2.f * x)); }

typedef __bf16 bf16x8 __attribute__((ext_vector_type(8)));
typedef float f32x4 __attribute__((ext_vector_type(4)));

#define MFMA16(a, b, c) __builtin_amdgcn_mfma_f32_16x16x32_bf16(a, b, c, 0, 0, 0)

DEVI void gll16(const void* g, void* l) {
  __builtin_amdgcn_global_load_lds((const __attribute__((address_space(1))) void*)g,
                                   (__attribute__((address_space(3))) void*)l, 16, 0, 0);
}

// monotonic total-order map for f32 bits
DEVI u32 fmono(float s) {
  u32 x = __float_as_uint(s);
  return x ^ (((u32)((int)x >> 31)) | 0x80000000u);
}

// descending compare-exchange (max to lower index)
DEVI void ced(u32& a, u32& b) {
  u32 hi = max(a, b), lo = min(a, b);
  a = hi; b = lo;
}
// Batcher odd-even merge sort, 8 elems, descending (19 CE)
DEVI void sort8_desc(u32* v) {
  ced(v[0], v[1]); ced(v[2], v[3]); ced(v[4], v[5]); ced(v[6], v[7]);
  ced(v[0], v[2]); ced(v[1], v[3]); ced(v[4], v[6]); ced(v[5], v[7]);
  ced(v[1], v[2]); ced(v[5], v[6]);
  ced(v[0], v[4]); ced(v[1], v[5]); ced(v[2], v[6]); ced(v[3], v[7]);
  ced(v[2], v[4]); ced(v[3], v[5]);
  ced(v[1], v[2]); ced(v[3], v[4]); ced(v[5], v[6]);
}
// bitonic 8-sequence -> descending sorted (12 CE)
DEVI void bitonic8_desc(u32* v) {
  ced(v[0], v[4]); ced(v[1], v[5]); ced(v[2], v[6]); ced(v[3], v[7]);
  ced(v[0], v[2]); ced(v[1], v[3]); ced(v[4], v[6]); ced(v[5], v[7]);
  ced(v[0], v[1]); ced(v[2], v[3]); ced(v[4], v[5]); ced(v[6], v[7]);
}
// a,b desc-sorted 8-lists -> a = top-8 of union, desc sorted
DEVI void merge_top8(u32* a, const u32* b) {
#pragma unroll
  for (int j = 0; j < 8; ++j) a[j] = max(a[j], b[7 - j]);
  bitonic8_desc(a);
}

// ---------------- input dtype detect: 0 = bf16, 1 = fp32 ----------------
__global__ void detect_kernel(const u16* __restrict__ x, int* __restrict__ flag) {
  if (threadIdx.x == 0 && blockIdx.x == 0) {
    int f = 0;
    for (int i = 0; i < 64; ++i) {
      u16 u = x[2 * i];  // low half if fp32
      int e = (u >> 7) & 0xFF;
      if (e > 131) f = 1;  // |val| >= 32 impossible for randn bf16
    }
    *flag = f;
  }
}

// ---------------- fused convert: all inputs -> bf16 arena, one dispatch ----------------
struct CvtArgs {
  const void* src[23];
  int aoff[23];
  int n[23];
  int total;
};

__global__ __launch_bounds__(256) void convert_fused(CvtArgs a, u16* __restrict__ arena,
                                                     const int* __restrict__ flag) {
  int e4 = (blockIdx.x * 256 + threadIdx.x) * 4;
  if (e4 >= a.total) return;
  const char* sp = (const char*)a.src[0];
  int rel = e4, cnt = a.n[0];
#pragma unroll
  for (int j = 1; j < 23; ++j)
    if (e4 >= a.aoff[j]) { sp = (const char*)a.src[j]; rel = e4 - a.aoff[j]; cnt = a.n[j]; }
  const bool f32 = (*flag != 0);
  if (rel + 3 < cnt) {
    if (f32) {
      float4 v = *(const float4*)(sp + (size_t)rel * 4);
      uint2 o;
      o.x = pack2(v.x, v.y);
      o.y = pack2(v.z, v.w);
      *(uint2*)(arena + e4) = o;
    } else {
      *(uint2*)(arena + e4) = *(const uint2*)(sp + (size_t)rel * 2);
    }
  } else {
#pragma unroll
    for (int k = 0; k < 4; ++k) {
      u16 o = 0;
      if (rel + k < cnt)
        o = f32 ? f2b(((const float*)sp)[rel + k]) : ((const u16*)sp)[rel + k];
      arena[e4 + k] = o;
    }
  }
}

// ---------------- bias concat: bqkv=[bq|bk|bv], bkv=[bk|bv] ----------------
__global__ void biascat_kernel(const u16* __restrict__ bq, const u16* __restrict__ bk,
                               const u16* __restrict__ bv, u16* __restrict__ bqkv,
                               u16* __restrict__ bkv) {
  int t = threadIdx.x;  // 512
  bqkv[t] = bq[t];
  bqkv[512 + t] = bk[t];
  bqkv[1024 + t] = bv[t];
  bkv[t] = bk[t];
  bkv[512 + t] = bv[t];
}

// ---------------- GEMM: m97 pattern + XCD swizzle + coalesced epilogue + 2-PHASE PIPELINE --
// BK=32, double-buffered staging (2x16KB) aliased under the 34.8KB epilogue buffer ->
// occupancy 4 (NOT 5: unified VGPR+AGPR needs ~112 regs/lane; bound 5 => 102 => spill,
// measured R8: WRITE_SIZE 124->305MB scratch traffic). Per iteration: issue next tile's
// gll16 BEFORE ds_read+MFMA of current; trailing __syncthreads drains prefetch AFTER
// compute -> HBM latency hidden (T3 minimum 2-phase recipe).
template <int ACT>
__global__ __launch_bounds__(256, 4) void gemm_bt(
    const u16* __restrict__ A, const u16* __restrict__ Bt,
    const u16* __restrict__ bias, u16* __restrict__ Co, int Mtot, int Ntot, int nby) {
  __shared__ __align__(16) u16 smem[128 * 136];  // staging dbuf (32KB) / epilogue st (34.8KB)
  u16* const aB0 = smem;
  u16* const aB1 = smem + 4096;
  u16* const bB0 = smem + 8192;
  u16* const bB1 = smem + 12288;
  const int tid = threadIdx.x;
  const int lane = tid & 63;
  const int w = tid >> 6;
  const int quad = lane >> 4;
  const int l15 = lane & 15;

  const int nwg = gridDim.x;
  const int orig = blockIdx.x;
  const int xcd = orig & 7, sq = orig >> 3;
  const int qd = nwg >> 3, rm = nwg & 7;
  const int wg = (xcd < rm ? xcd * (qd + 1) : rm * (qd + 1) + (xcd - rm) * qd) + sq;
  const int m0 = (wg / nby) * 128;
  const int n0 = (wg % nby) * 128;

  const int wm = (w & 1) << 6;
  const int wn = (w >> 1) << 6;

  f32x4 acc[4][4] = {};

  const u16* ga[2];
  const u16* gb[2];
#pragma unroll
  for (int q = 0; q < 2; ++q) {
    int j = q * 256 + tid;
    int r = j >> 2, s = j & 3;
    int c = (s ^ ((r >> 1) & 3)) * 8;
    int ra = m0 + r;
    if (ra >= Mtot) ra = Mtot - 1;
    ga[q] = A + (size_t)ra * 512 + c;
    gb[q] = Bt + (size_t)(n0 + r) * 512 + c;
  }

  auto stage = [&](int p, int ko) {
    u16* ab = p ? aB1 : aB0;
    u16* bb = p ? bB1 : bB0;
#pragma unroll
    for (int q = 0; q < 2; ++q) {
      int j = q * 256 + tid;
      gll16(ga[q] + ko * 32, ab + j * 8);
      gll16(gb[q] + ko * 32, bb + j * 8);
    }
  };

  stage(0, 0);
  __syncthreads();
  int cur = 0;
  for (int ko = 0; ko < 16; ++ko) {
    if (ko < 15) stage(cur ^ 1, ko + 1);
    u16* ab = cur ? aB1 : aB0;
    u16* bb = cur ? bB1 : bB0;
    bf16x8 af[4], bfr[4];
#pragma unroll
    for (int i = 0; i < 4; ++i) {
      int r = wm + i * 16 + l15;
      af[i] = *(const bf16x8*)(ab + (((r << 2) | (quad ^ ((r >> 1) & 3)))) * 8);
      int rn = wn + i * 16 + l15;
      bfr[i] = *(const bf16x8*)(bb + (((rn << 2) | (quad ^ ((rn >> 1) & 3)))) * 8);
    }
#pragma unroll
    for (int i = 0; i < 4; ++i)
#pragma unroll
      for (int jn = 0; jn < 4; ++jn)
        acc[i][jn] = MFMA16(af[i], bfr[jn], acc[i][jn]);
    __syncthreads();
    cur ^= 1;
  }

  // epilogue: bias/act -> bf16 into LDS st[128][136], then coalesced 16B stores
  u16* st = smem;
#pragma unroll
  for (int jn = 0; jn < 4; ++jn) {
    int coll = wn + jn * 16 + l15;
    float bv = b2f(bias[n0 + coll]);
#pragma unroll
    for (int i = 0; i < 4; ++i) {
      int rowb = wm + i * 16 + quad * 4;
#pragma unroll
      for (int rr = 0; rr < 4; ++rr) {
        float vv = acc[i][jn][rr] + bv;
        if (ACT) vv = fmaxf(vv, 0.f);
        st[(rowb + rr) * 136 + coll] = f2b(vv);
      }
    }
  }
  __syncthreads();
#pragma unroll
  for (int t = 0; t < 8; ++t) {
    int idx = (t * 256 + tid) * 8;  // u16 units within 128x128 tile
    int r = idx >> 7;
    int c = idx & 127;
    int row = m0 + r;
    if (row < Mtot) {
      uint4 v = *(const uint4*)(st + r * 136 + c);
      *(uint4*)(Co + (size_t)row * Ntot + n0 + c) = v;
    }
  }
}

// ---------------- gate GEMM + gates fused (2-phase pipelined) ----------------
__global__ __launch_bounds__(256, 4) void gemm_gates(
    const u16* __restrict__ A, const u16* __restrict__ WmgTp,
    const u16* __restrict__ bmg, const u16* __restrict__ gi,
    const u16* __restrict__ memfin, const u16* __restrict__ mem_in,
    const u16* __restrict__ ibp, const u16* __restrict__ fbp,
    u16* __restrict__ nmbf, void* __restrict__ outp, const int* __restrict__ flag,
    int Mtot) {
  __shared__ __align__(16) u16 smem[128 * 136];
  u16* const aB0 = smem;
  u16* const aB1 = smem + 4096;
  u16* const bB0 = smem + 8192;
  u16* const bB1 = smem + 12288;
  const int tid = threadIdx.x;
  const int lane = tid & 63;
  const int w = tid >> 6;
  const int quad = lane >> 4;
  const int l15 = lane & 15;

  const int nwg = gridDim.x;
  const int orig = blockIdx.x;
  const int xcd = orig & 7, sq = orig >> 3;
  const int qd = nwg >> 3, rm = nwg & 7;
  const int wg = (xcd < rm ? xcd * (qd + 1) : rm * (qd + 1) + (xcd - rm) * qd) + sq;
  const int m0 = (wg >> 3) * 128;    // nby = 8
  const int n0h = (wg & 7) * 64;     // col offset within [0,512)

  const int wm = (w & 1) << 6;
  const int wn = (w >> 1) << 6;

  f32x4 acc[4][4] = {};

  const u16* ga[2];
  const u16* gb[2];
#pragma unroll
  for (int q = 0; q < 2; ++q) {
    int j = q * 256 + tid;
    int r = j >> 2, s = j & 3;
    int c = (s ^ ((r >> 1) & 3)) * 8;
    int ra = m0 + r;
    if (ra >= Mtot) ra = Mtot - 1;
    ga[q] = A + (size_t)ra * 512 + c;
    int br = (r < 64) ? (n0h + r) : (512 + n0h + r - 64);  // ig half | fg half
    gb[q] = WmgTp + (size_t)br * 512 + c;
  }

  auto stage = [&](int p, int ko) {
    u16* ab = p ? aB1 : aB0;
    u16* bb = p ? bB1 : bB0;
#pragma unroll
    for (int q = 0; q < 2; ++q) {
      int j = q * 256 + tid;
      gll16(ga[q] + ko * 32, ab + j * 8);
      gll16(gb[q] + ko * 32, bb + j * 8);
    }
  };

  stage(0, 0);
  __syncthreads();
  int cur = 0;
  for (int ko = 0; ko < 16; ++ko) {
    if (ko < 15) stage(cur ^ 1, ko + 1);
    u16* ab = cur ? aB1 : aB0;
    u16* bb = cur ? bB1 : bB0;
    bf16x8 af[4], bfr[4];
#pragma unroll
    for (int i = 0; i < 4; ++i) {
      int r = wm + i * 16 + l15;
      af[i] = *(const bf16x8*)(ab + (((r << 2) | (quad ^ ((r >> 1) & 3)))) * 8);
      int rn = wn + i * 16 + l15;
      bfr[i] = *(const bf16x8*)(bb + (((rn << 2) | (quad ^ ((rn >> 1) & 3)))) * 8);
    }
#pragma unroll
    for (int i = 0; i < 4; ++i)
#pragma unroll
      for (int jn = 0; jn < 4; ++jn)
        acc[i][jn] = MFMA16(af[i], bfr[jn], acc[i][jn]);
    __syncthreads();
    cur ^= 1;
  }

  // stage gm (bf16, with bmg bias) into LDS: cols 0..63 = ig, 64..127 = fg
  u16* st = smem;
#pragma unroll
  for (int jn = 0; jn < 4; ++jn) {
    int coll = wn + jn * 16 + l15;
    int bcol = (coll < 64) ? (n0h + coll) : (512 + n0h + coll - 64);
    float bv = b2f(bmg[bcol]);
#pragma unroll
    for (int i = 0; i < 4; ++i) {
      int rowb = wm + i * 16 + quad * 4;
#pragma unroll
      for (int rr = 0; rr < 4; ++rr)
        st[(rowb + rr) * 136 + coll] = f2b(acc[i][jn][rr] + bv);
    }
  }
  __syncthreads();

  const float ib = b2f(ibp[0]);
  const float fb = b2f(fbp[0]);
  const bool of32 = (*flag != 0);
#pragma unroll
  for (int t = 0; t < 4; ++t) {
    int chunk = t * 256 + tid;        // 1024 chunks of 8 elems = 128 rows x 64 cols
    int rl = chunk >> 3;
    int c8 = (chunk & 7) * 8;
    int row = m0 + rl;
    if (row >= Mtot) continue;
    int b = row / 1290;
    size_t gidx = (size_t)row * 512 + n0h + c8;
    uint4 uig = *(const uint4*)(st + rl * 136 + c8);
    uint4 ufg = *(const uint4*)(st + rl * 136 + 64 + c8);
    uint4 ugi = *(const uint4*)(gi + b * 1024 + n0h + c8);
    uint4 ugf = *(const uint4*)(gi + b * 1024 + 512 + n0h + c8);
    uint4 umf = *(const uint4*)(memfin + gidx);
    uint4 umi = *(const uint4*)(mem_in + gidx);
    const u32* pig = (const u32*)&uig;
    const u32* pfg = (const u32*)&ufg;
    const u32* pgi = (const u32*)&ugi;
    const u32* pgf = (const u32*)&ugf;
    const u32* pmf = (const u32*)&umf;
    const u32* pmi = (const u32*)&umi;
    float v[8];
#pragma unroll
    for (int k = 0; k < 4; ++k) {
      float ig0 = sigm(blo(pig[k]) + blo(pgi[k]) + ib);
      float ig1 = sigm(bhi(pig[k]) + bhi(pgi[k]) + ib);
      float fg0 = sigm(blo(pfg[k]) + blo(pgf[k]) + fb);
      float fg1 = sigm(bhi(pfg[k]) + bhi(pgf[k]) + fb);
      v[2 * k] = ig0 * ftanh(blo(pmf[k])) + fg0 * blo(pmi[k]);
      v[2 * k + 1] = ig1 * ftanh(bhi(pmf[k])) + fg1 * bhi(pmi[k]);
    }
    uint4 o;
    u32* po = (u32*)&o;
#pragma unroll
    for (int k = 0; k < 4; ++k) po[k] = pack2(v[2 * k], v[2 * k + 1]);
    *(uint4*)(nmbf + gidx) = o;
    if (of32) {
      float4 f0, f1;
      f0.x = v[0]; f0.y = v[1]; f0.z = v[2]; f0.w = v[3];
      f1.x = v[4]; f1.y = v[5]; f1.z = v[6]; f1.w = v[7];
      *(float4*)((float*)outp + gidx) = f0;
      *(float4*)((float*)outp + gidx + 4) = f1;
    } else {
      *(uint4*)((u16*)outp + gidx) = o;
    }
  }
}

// ---------------- weight transpose ----------------
__global__ __launch_bounds__(256) void transpose_kernel(const u16* __restrict__ in,
                                                        u16* __restrict__ outb, int K, int N) {
  __shared__ u16 tile[32][33];
  const int tx = threadIdx.x & 31, ty = threadIdx.x >> 5;
  const int bx = blockIdx.x * 32;
  const int by = blockIdx.y * 32;
#pragma unroll
  for (int i = 0; i < 32; i += 8) tile[ty + i][tx] = in[(size_t)(by + ty + i) * N + bx + tx];
  __syncthreads();
#pragma unroll
  for (int i = 0; i < 32; i += 8) outb[(size_t)(bx + ty + i) * K + by + tx] = tile[tx][ty + i];
}

// ---------------- tanh(memory) ----------------
__global__ void tanhmem_kernel(const u16* __restrict__ mi, u16* __restrict__ th, int n8) {
  int i = blockIdx.x * 256 + threadIdx.x;
  if (i >= n8) return;
  uint4 u = ((const uint4*)mi)[i];
  uint4 t;
  t.x = pack2(ftanh(blo(u.x)), ftanh(bhi(u.x)));
  t.y = pack2(ftanh(blo(u.y)), ftanh(bhi(u.y)));
  t.z = pack2(ftanh(blo(u.z)), ftanh(bhi(u.z)));
  t.w = pack2(ftanh(blo(u.w)), ftanh(bhi(u.w)));
  ((uint4*)th)[i] = t;
}

// ---------------- rmean ----------------
__global__ void redmean_kernel(const u16* __restrict__ inp, const u16* __restrict__ repw,
                               u16* __restrict__ outb) {
  const int b = blockIdx.x;
  const int c = blockIdx.y * 256 + threadIdx.x;
  const float rw = b2f(repw[c]);
  float s = 0.f;
  for (int t = 0; t < 128; ++t)
    s += fmaxf(rw * b2f(inp[(size_t)(b * 128 + t) * 512 + c]), 0.f);
  outb[b * 512 + c] = f2b(s * (1.f / 128.f));
}

// ---------------- LayerNorm (4 rows/block, vectorized 16B loads: G13) ----------------
// Lane owns 8 CONTIGUOUS elems (lane*8..lane*8+7): one uint4 per tensor instead of 8
// scalar 2B loads. Reduction over the full 512-row is order-insensitive at f32 (~1e-7).
__global__ __launch_bounds__(256) void ln_kernel(const u16* __restrict__ src,
                                                 const u16* __restrict__ addb,
                                                 u16* __restrict__ dst,
                                                 const u16* __restrict__ g,
                                                 const u16* __restrict__ bb) {
  const int row = blockIdx.x * 4 + (threadIdx.x >> 6);
  const int lane = threadIdx.x & 63;
  const size_t base = (size_t)row * 512 + lane * 8;
  uint4 us = *(const uint4*)(src + base);
  uint4 ua = *(const uint4*)(addb + base);
  const u32* ps = (const u32*)&us;
  const u32* pa = (const u32*)&ua;
  float x[8];
  float s = 0.f;
#pragma unroll
  for (int k = 0; k < 4; ++k) {
    x[2 * k] = blo(ps[k]) + blo(pa[k]);
    x[2 * k + 1] = bhi(ps[k]) + bhi(pa[k]);
    s += x[2 * k] + x[2 * k + 1];
  }
#pragma unroll
  for (int off = 32; off > 0; off >>= 1) s += __shfl_xor(s, off, 64);
  const float mu = s * (1.f / 512.f);
  float v = 0.f;
#pragma unroll
  for (int i = 0; i < 8; ++i) {
    float d = x[i] - mu;
    v = fmaf(d, d, v);
  }
#pragma unroll
  for (int off = 32; off > 0; off >>= 1) v += __shfl_xor(v, off, 64);
  const float rstd = rsqrtf(v * (1.f / 512.f) + 1e-5f);
  uint4 ug = *(const uint4*)(g + lane * 8);
  uint4 ub = *(const uint4*)(bb + lane * 8);
  const u32* pg = (const u32*)&ug;
  const u32* pb = (const u32*)&ub;
  uint4 o;
  u32* po = (u32*)&o;
#pragma unroll
  for (int k = 0; k < 4; ++k) {
    float y0 = fmaf((x[2 * k] - mu) * rstd, blo(pg[k]), blo(pb[k]));
    float y1 = fmaf((x[2 * k + 1] - mu) * rstd, bhi(pg[k]), bhi(pb[k]));
    po[k] = pack2(y0, y1);
  }
  *(uint4*)(dst + base) = o;
}

// ---------------- attention 1 (MFMA): 1290 q (mem), 128 k (inp), top-8 mask ----------------
__global__ __launch_bounds__(256, 3) void attn1_mfma(const u16* __restrict__ q,
                                                     const u16* __restrict__ kb,
                                                     const u16* __restrict__ vb,
                                                     u16* __restrict__ o, int ldkv) {
  __shared__ __align__(16) u16 Pl[128 * 136];  // masked P [q][k]; rows 0..60 alias Kl
  __shared__ __align__(16) u16 VT[64 * 136];   // V^T [d][k]
  __shared__ float lbuf[128];                  // 1/l per local query
  u16* Kl = Pl;                                // phase-1 alias: swizzled K [key][dim]

  const int tid = threadIdx.x;
  const int lane = tid & 63;
  const int w = tid >> 6;
  const int quad = lane >> 4;
  const int l15 = lane & 15;
  const int qb = blockIdx.x;
  const int bh = blockIdx.y;
  const int b = bh >> 3, h = bh & 7;

  // stage K swizzled (gll16) into Kl
#pragma unroll
  for (int qq = 0; qq < 4; ++qq) {
    int j = qq * 256 + tid;
    int r = j >> 3, s = j & 7;
    gll16(kb + (size_t)(b * 128 + r) * ldkv + h * 64 + (s ^ (r & 7)) * 8, Kl + j * 8);
  }
  // stage V transposed: per wave, 64 consecutive keys per d-row write (2-way banks, free)
#pragma unroll
  for (int p = 0; p < 4; ++p) {
    int key = (tid & 63) + 64 * (p & 1);
    int dc = w + 4 * (p >> 1);
    uint4 u = *(const uint4*)(vb + (size_t)(b * 128 + key) * ldkv + h * 64 + dc * 8);
    u16 tmp[8];
    *(uint4*)tmp = u;
#pragma unroll
    for (int jj = 0; jj < 8; ++jj) VT[(dc * 8 + jj) * 136 + key] = tmp[jj];
  }

  // Q fragments (B-operand): col = query, quad picks dim-chunk
  bf16x8 bq[2][2];
  {
    int ra = min(qb * 128 + w * 32 + l15, 1289);
    int rb_ = min(qb * 128 + w * 32 + 16 + l15, 1289);
    const u16* qa = q + (size_t)(b * 1290 + ra) * 512 + h * 64 + quad * 8;
    const u16* qc = q + (size_t)(b * 1290 + rb_) * 512 + h * 64 + quad * 8;
    bq[0][0] = *(const bf16x8*)(qa);
    bq[0][1] = *(const bf16x8*)(qa + 32);
    bq[1][0] = *(const bf16x8*)(qc);
    bq[1][1] = *(const bf16x8*)(qc + 32);
  }
  __syncthreads();

  // S^T = K.Q^T : thread holds query (w*32+i*16+l15), k = jn*16+quad*4+rr
  f32x4 sa[2][8] = {};
#pragma unroll
  for (int ks = 0; ks < 2; ++ks) {
#pragma unroll
    for (int jn = 0; jn < 8; ++jn) {
      int n = jn * 16 + l15;
      int cch = ks * 4 + quad;
      bf16x8 ak = *(const bf16x8*)(Kl + (n * 8 + (cch ^ (n & 7))) * 8);
      sa[0][jn] = MFMA16(ak, bq[0][ks], sa[0][jn]);
      sa[1][jn] = MFMA16(ak, bq[1][ks], sa[1][jn]);
    }
  }
  __syncthreads();  // all Kl reads done before P overwrites the aliased region

  const u32 ibase = 127u - (u32)(quad * 4);
#pragma unroll
  for (int i = 0; i < 2; ++i) {
    const int qi = w * 32 + i * 16 + l15;
    // build packed keys (scale scores in place; sa keeps f32 for the exp pass)
    u32 g[4][8];
#pragma unroll
    for (int jn = 0; jn < 8; ++jn)
#pragma unroll
      for (int rr = 0; rr < 4; ++rr) {
        float s = sa[i][jn][rr] * 0.125f;
        sa[i][jn][rr] = s;
        g[jn >> 1][(jn & 1) * 4 + rr] =
            (fmono(s) & 0xFFFFFF80u) | (ibase - (u32)(jn * 16 + rr));
      }
    // local top-8: 4x sort8 + merge tree
    sort8_desc(g[0]); sort8_desc(g[1]); sort8_desc(g[2]); sort8_desc(g[3]);
    merge_top8(g[0], g[1]);
    merge_top8(g[2], g[3]);
    merge_top8(g[0], g[2]);
    u32* tv = g[0];
    // merge sorted top-8 lists across quads (xor 16, then 32)
#pragma unroll
    for (int off = 16; off < 64; off <<= 1) {
      u32 pv[8];
#pragma unroll
      for (int j = 0; j < 8; ++j) pv[j] = (u32)__shfl_xor((int)tv[7 - j], off, 64);
#pragma unroll
      for (int j = 0; j < 8; ++j) tv[j] = max(tv[j], pv[j]);
      bitonic8_desc(tv);
    }
    const u32 t8 = tv[7];  // 8th largest packed key; membership = (key >= t8)
    // decode running max (25-bit truncated; <= true max, safe for exp)
    u32 mb = tv[0] & 0xFFFFFF80u;
    u32 xm = (mb & 0x80000000u) ? (mb ^ 0x80000000u) : ~mb;
    const float mx = __uint_as_float(xm);
    // single pass: denom over all 128 + masked unnormalized P write
    float lsum = 0.f;
#pragma unroll
    for (int jn = 0; jn < 8; ++jn) {
      u16 pr[4];
#pragma unroll
      for (int rr = 0; rr < 4; ++rr) {
        float s = sa[i][jn][rr];
        float e = __expf(s - mx);
        lsum += e;
        u32 kk = (fmono(s) & 0xFFFFFF80u) | (ibase - (u32)(jn * 16 + rr));
        pr[rr] = (kk >= t8) ? f2b(e) : (u16)0;
      }
      uint2 st;
      st.x = (u32)pr[0] | ((u32)pr[1] << 16);
      st.y = (u32)pr[2] | ((u32)pr[3] << 16);
      *(uint2*)(Pl + qi * 136 + jn * 16 + quad * 4) = st;
    }
    lsum += __shfl_xor(lsum, 16, 64);
    lsum += __shfl_xor(lsum, 32, 64);
    if (quad == 0) lbuf[qi] = 1.f / lsum;
  }
  __syncthreads();

  // O = P.V  (A = masked P rows, B = VT rows)
  f32x4 oa[2][4] = {};
#pragma unroll
  for (int kc = 0; kc < 4; ++kc) {
    bf16x8 ap[2];
#pragma unroll
    for (int i = 0; i < 2; ++i)
      ap[i] = *(const bf16x8*)(Pl + (w * 32 + i * 16 + l15) * 136 + kc * 32 + quad * 8);
#pragma unroll
    for (int jd = 0; jd < 4; ++jd) {
      bf16x8 bv_ = *(const bf16x8*)(VT + (jd * 16 + l15) * 136 + kc * 32 + quad * 8);
      oa[0][jd] = MFMA16(ap[0], bv_, oa[0][jd]);
      oa[1][jd] = MFMA16(ap[1], bv_, oa[1][jd]);
    }
  }

  // epilogue: scale rows by 1/l, write bf16
#pragma unroll
  for (int i = 0; i < 2; ++i) {
    int rowl = w * 32 + i * 16 + quad * 4;
#pragma unroll
    for (int rr = 0; rr < 4; ++rr) {
      int qg = qb * 128 + rowl + rr;
      if (qg < 1290) {
        float il = lbuf[rowl + rr];
        u16* orow = o + (size_t)(b * 1290 + qg) * 512 + h * 64;
#pragma unroll
        for (int jd = 0; jd < 4; ++jd) orow[jd * 16 + l15] = f2b(oa[i][jd][rr] * il);
      }
    }
  }
}

// ---------------- attention 2 (MFMA flash): 128 q (inp), 1290 k (next_memory) ----------------
__global__ __launch_bounds__(256, 2) void attn2_mfma(const u16* __restrict__ q2,
                                                     const u16* __restrict__ k2,
                                                     const u16* __restrict__ v2,
                                                     float* __restrict__ pacc,
                                                     float* __restrict__ pml,
                                                     int ldq, int ldkv) {
  __shared__ __align__(16) u16 Kl[64 * 64];      // swizzled [key][dim]
  __shared__ __align__(16) u16 VT[64 * 72];      // [dim][key], stride 72
  __shared__ __align__(16) u16 Pl[4 * 32 * 72];  // per-wave P [32q][64k]
  const int tid = threadIdx.x;
  const int lane = tid & 63;
  const int w = tid >> 6;
  const int quad = lane >> 4;
  const int l15 = lane & 15;
  const int bh = blockIdx.x;
  const int b = bh >> 3, h = bh & 7;
  const int part = blockIdx.y;
  const int kstart = (part * 1290) >> 2;
  const int kend = ((part + 1) * 1290) >> 2;

  bf16x8 aq[2][2];
  {
    int r0 = b * 128 + w * 32 + l15;
    const u16* qa = q2 + (size_t)r0 * ldq + h * 64 + quad * 8;
    aq[0][0] = *(const bf16x8*)(qa);
    aq[0][1] = *(const bf16x8*)(qa + 32);
    aq[1][0] = *(const bf16x8*)(qa + (size_t)16 * ldq);
    aq[1][1] = *(const bf16x8*)(qa + (size_t)16 * ldq + 32);
  }

  f32x4 oa[2][4] = {};
  float m_[2][4], l_[2][4];
#pragma unroll
  for (int i = 0; i < 2; ++i)
#pragma unroll
    for (int r = 0; r < 4; ++r) { m_[i][r] = -1e30f; l_[i][r] = 0.f; }

  const int nk = kend - kstart;
  for (int kt = 0; kt < nk; kt += 64) {
    __syncthreads();
    // stage K swizzled (gll16)
#pragma unroll
    for (int qq = 0; qq < 2; ++qq) {
      int j = qq * 256 + tid;
      int r = j >> 3, s = j & 7;
      int kg = kstart + kt + r;
      if (kg >= kend) kg = kend - 1;
      gll16(k2 + (size_t)(b * 1290 + kg) * ldkv + h * 64 + (s ^ (r & 7)) * 8, Kl + j * 8);
    }
    // stage V transposed: lane r = key, dc = dim chunk (write banks: const + r/2 -> 2-way free)
    {
      int r = tid & 63;
      int kg = kstart + kt + r;
      if (kg >= kend) kg = kend - 1;
      const u16* vrow = v2 + (size_t)(b * 1290 + kg) * ldkv + h * 64;
#pragma unroll
      for (int p = 0; p < 2; ++p) {
        int dc = (tid >> 6) + p * 4;
        uint4 u = *(const uint4*)(vrow + dc * 8);
        u16 tmp[8];
        *(uint4*)tmp = u;
#pragma unroll
        for (int jj = 0; jj < 8; ++jj) VT[(dc * 8 + jj) * 72 + r] = tmp[jj];
      }
    }
    __syncthreads();

    // S = Q.K^T
    f32x4 sa[2][4] = {};
#pragma unroll
    for (int ks = 0; ks < 2; ++ks) {
#pragma unroll
      for (int jn = 0; jn < 4; ++jn) {
        int n = jn * 16 + l15;
        int cch = ks * 4 + quad;
        bf16x8 bk = *(const bf16x8*)(Kl + (n * 8 + (cch ^ (n & 7))) * 8);
        sa[0][jn] = MFMA16(aq[0][ks], bk, sa[0][jn]);
        sa[1][jn] = MFMA16(aq[1][ks], bk, sa[1][jn]);
      }
    }

    // online softmax (C-layout: col=l15 is key, row=quad*4+r is query) + P to LDS
    u16* pw = Pl + w * (32 * 72);
#pragma unroll
    for (int i = 0; i < 2; ++i) {
      float rmax[4] = {-1e30f, -1e30f, -1e30f, -1e30f};
#pragma unroll
      for (int jn = 0; jn < 4; ++jn) {
        int kg = kstart + kt + jn * 16 + l15;
        bool val = kg < kend;
#pragma unroll
        for (int r = 0; r < 4; ++r) {
          float s = sa[i][jn][r] * 0.125f;
          s = val ? s : -1e30f;
          sa[i][jn][r] = s;
          rmax[r] = fmaxf(rmax[r], s);
        }
      }
#pragma unroll
      for (int off = 1; off < 16; off <<= 1)
#pragma unroll
        for (int r = 0; r < 4; ++r) rmax[r] = fmaxf(rmax[r], __shfl_xor(rmax[r], off, 64));
      float alpha[4];
#pragma unroll
      for (int r = 0; r < 4; ++r) {
        float mn = fmaxf(m_[i][r], rmax[r]);
        alpha[r] = __expf(m_[i][r] - mn);
        m_[i][r] = mn;
      }
      float lsum[4] = {0.f, 0.f, 0.f, 0.f};
#pragma unroll
      for (int jn = 0; jn < 4; ++jn)
#pragma unroll
        for (int r = 0; r < 4; ++r) {
          float p = __expf(sa[i][jn][r] - m_[i][r]);
          sa[i][jn][r] = p;
          lsum[r] += p;
        }
#pragma unroll
      for (int off = 1; off < 16; off <<= 1)
#pragma unroll
        for (int r = 0; r < 4; ++r) lsum[r] += __shfl_xor(lsum[r], off, 64);
#pragma unroll
      for (int r = 0; r < 4; ++r) l_[i][r] = l_[i][r] * alpha[r] + lsum[r];
#pragma unroll
      for (int jd = 0; jd < 4; ++jd)
#pragma unroll
        for (int r = 0; r < 4; ++r) oa[i][jd][r] *= alpha[r];
#pragma unroll
      for (int jn = 0; jn < 4; ++jn) {
        int col = jn * 16 + l15;
#pragma unroll
        for (int r = 0; r < 4; ++r)
          pw[(i * 16 + quad * 4 + r) * 72 + col] = f2b(sa[i][jn][r]);
      }
    }

    // O += P.V   (A = P from per-wave LDS, B = VT)
#pragma unroll
    for (int ks = 0; ks < 2; ++ks) {
      bf16x8 ap[2];
#pragma unroll
      for (int i = 0; i < 2; ++i)
        ap[i] = *(const bf16x8*)(pw + (i * 16 + l15) * 72 + ks * 32 + quad * 8);
#pragma unroll
      for (int jd = 0; jd < 4; ++jd) {
        bf16x8 bv_ = *(const bf16x8*)(VT + (jd * 16 + l15) * 72 + ks * 32 + quad * 8);
        oa[0][jd] = MFMA16(ap[0], bv_, oa[0][jd]);
        oa[1][jd] = MFMA16(ap[1], bv_, oa[1][jd]);
      }
    }
  }

  // store partials (C-layout scatter)
  float* pa = pacc + (size_t)(part * 256 + bh) * 128 * 64;
#pragma unroll
  for (int i = 0; i < 2; ++i) {
    int row = w * 32 + i * 16 + quad * 4;
#pragma unroll
    for (int r = 0; r < 4; ++r)
#pragma unroll
      for (int jd = 0; jd < 4; ++jd)
        pa[(size_t)(row + r) * 64 + jd * 16 + l15] = oa[i][jd][r];
    if (l15 == 0) {
#pragma unroll
      for (int r = 0; r < 4; ++r) {
        size_t pi = (size_t)(part * 256 + bh) * 128 + row + r;
        pml[pi * 2 + 0] = m_[i][r];
        pml[pi * 2 + 1] = l_[i][r];
      }
    }
  }
}

// ---------------- attn2 merge: 4 queries/block (1 wave each) ----------------
__global__ __launch_bounds__(256) void attn2_merge(const float* __restrict__ pacc,
                                                   const float* __restrict__ pml,
                                                   void* __restrict__ outp,
                                                   const int* __restrict__ flag) {
  const int qi = blockIdx.x * 4 + (threadIdx.x >> 6);  // bh*128 + t
  const int bh = qi >> 7, t = qi & 127;
  const int b = bh >> 3, h = bh & 7;
  const int lane = threadIdx.x & 63;
  float mv[4], lv[4];
  float m0 = -1e30f;
#pragma unroll
  for (int i = 0; i < 4; ++i) {
    size_t pi = (size_t)(i * 256 + bh) * 128 + t;
    mv[i] = pml[pi * 2];
    lv[i] = pml[pi * 2 + 1];
    m0 = fmaxf(m0, mv[i]);
  }
  float L = 0.f, accd = 0.f;
#pragma unroll
  for (int i = 0; i < 4; ++i) {
    size_t pi = (size_t)(i * 256 + bh) * 128 + t;
    float e = __expf(mv[i] - m0);
    L += lv[i] * e;
    accd += pacc[pi * 64 + lane] * e;
  }
  float v = accd / L;
  size_t off = (size_t)41280 * 512 + ((size_t)(b * 128 + t) * 512 + h * 64 + lane);
  if (*flag) ((float*)outp)[off] = v; else ((u16*)outp)[off] = f2b(v);
}

extern "C" void kernel_launch(void* const* d_in, const int* in_sizes, int n_in,
                              void* d_out, int out_size, void* d_ws, size_t ws_size,
                              hipStream_t stream) {
  (void)out_size; (void)ws_size;
  char* ws = (char*)d_ws;
  size_t off = 0;
  auto alloc = [&](size_t bytes) {
    char* p = ws + off;
    off += (bytes + 255) & ~(size_t)255;
    return (void*)p;
  };

  int* flag = (int*)alloc(256);

  size_t aoffs[32];
  size_t total = 0;
  for (int i = 0; i < n_in; ++i) {
    aoffs[i] = total;
    total += ((size_t)in_sizes[i] + 127) & ~(size_t)127;
  }
  u16* arena = (u16*)alloc(total * 2);

  const u16* c_ipts = arena + aoffs[0];
  const u16* c_mem  = arena + aoffs[1];
  const u16* c_Wq = arena + aoffs[2];  const u16* c_bq = arena + aoffs[3];
  const u16* c_Wk = arena + aoffs[4];  const u16* c_bk = arena + aoffs[5];
  const u16* c_Wv = arena + aoffs[6];  const u16* c_bv = arena + aoffs[7];
  const u16* c_Wm = arena + aoffs[8];  const u16* c_bm = arena + aoffs[9];
  const u16* c_g1 = arena + aoffs[10]; const u16* c_b1 = arena + aoffs[11];
  const u16* c_g2 = arena + aoffs[12]; const u16* c_b2 = arena + aoffs[13];
  const u16* c_Wp = arena + aoffs[14]; const u16* c_bp = arena + aoffs[15];
  const u16* c_repw = arena + aoffs[16];
  const u16* c_Wig = arena + aoffs[17]; const u16* c_big = arena + aoffs[18];
  const u16* c_Wmg = arena + aoffs[19]; const u16* c_bmg = arena + aoffs[20];
  const u16* c_fb = arena + aoffs[21];
  const u16* c_ib = arena + aoffs[22];

  u16* WqkvT = (u16*)alloc((size_t)1536 * 512 * 2);  // rows: Wq^T | Wk^T | Wv^T
  u16* WmT = (u16*)alloc(512 * 512 * 2);
  u16* WpT = (u16*)alloc(512 * 512 * 2);
  u16* WigT = (u16*)alloc(512 * 1024 * 2);
  u16* WmgT = (u16*)alloc(512 * 1024 * 2);
  u16* bqkv = (u16*)alloc(1536 * 2);
  u16* bkv = (u16*)alloc(1024 * 2);
  u16* inp = (u16*)alloc((size_t)4096 * 512 * 2);
  u16* qkvbuf = (u16*)alloc((size_t)4096 * 1536 * 2);  // [row][q|k|v]
  u16* rmean = (u16*)alloc(32 * 512 * 2);
  u16* gi = (u16*)alloc(32 * 1024 * 2);
  u16* membf = (u16*)alloc((size_t)41280 * 512 * 2);
  u16* qbuf = (u16*)alloc((size_t)41280 * 512 * 2);
  u16* obuf = (u16*)alloc((size_t)41280 * 512 * 2);   // + gmbuf = contiguous 84.5MB region
  u16* gmbuf = (u16*)alloc((size_t)41280 * 512 * 2);
  u16* nmbf = (u16*)alloc((size_t)41280 * 512 * 2);
  (void)gmbuf;
  u16* kvbuf = obuf;    // [41280][1024] spans obuf+gmbuf (both free at that point)
  float* pacc = (float*)(void*)qbuf;  // 33.5MB (qbuf dead after gemm_gates)
  float* pml = (float*)((char*)(void*)qbuf + (size_t)4 * 32768 * 64 * 4);

  detect_kernel<<<1, 64, 0, stream>>>((const u16*)d_in[0], flag);
  {
    CvtArgs ca;
    for (int i = 0; i < 23; ++i) {
      int ii = (i < n_in) ? i : (n_in - 1);
      ca.src[i] = d_in[ii];
      ca.aoff[i] = (int)aoffs[ii];
      ca.n[i] = in_sizes[ii];
    }
    ca.total = (int)total;
    convert_fused<<<(unsigned)((total / 4 + 255) / 256), 256, 0, stream>>>(ca, arena, flag);
  }
  biascat_kernel<<<1, 512, 0, stream>>>(c_bq, c_bk, c_bv, bqkv, bkv);

  transpose_kernel<<<dim3(16, 16), 256, 0, stream>>>(c_Wq, WqkvT, 512, 512);
  transpose_kernel<<<dim3(16, 16), 256, 0, stream>>>(c_Wk, WqkvT + (size_t)512 * 512, 512, 512);
  transpose_kernel<<<dim3(16, 16), 256, 0, stream>>>(c_Wv, WqkvT + (size_t)1024 * 512, 512, 512);
  transpose_kernel<<<dim3(16, 16), 256, 0, stream>>>(c_Wm, WmT, 512, 512);
  transpose_kernel<<<dim3(16, 16), 256, 0, stream>>>(c_Wp, WpT, 512, 512);
  transpose_kernel<<<dim3(32, 16), 256, 0, stream>>>(c_Wig, WigT, 512, 1024);
  transpose_kernel<<<dim3(32, 16), 256, 0, stream>>>(c_Wmg, WmgT, 512, 1024);

  gemm_bt<0><<<dim3(32 * 4), 256, 0, stream>>>(c_ipts, WpT, c_bp, inp, 4096, 512, 4);
  // fused QKV projection of inp: [4096][1536] = inp @ [Wq|Wk|Wv]
  gemm_bt<0><<<dim3(32 * 12), 256, 0, stream>>>(inp, WqkvT, bqkv, qkvbuf, 4096, 1536, 12);

  redmean_kernel<<<dim3(32, 2), 256, 0, stream>>>(inp, c_repw, rmean);
  gemm_bt<0><<<dim3(1 * 8), 256, 0, stream>>>(rmean, WigT, c_big, gi, 32, 1024, 8);

  const u16* memsrc = c_mem;
  for (int it = 0; it < 4; ++it) {
    gemm_bt<0><<<dim3(323 * 4), 256, 0, stream>>>(memsrc, WqkvT, c_bq, qbuf, 41280, 512, 4);
    attn1_mfma<<<dim3(11, 256), 256, 0, stream>>>(qbuf, qkvbuf + 512, qkvbuf + 1024, obuf, 1536);
    ln_kernel<<<dim3(10320), 256, 0, stream>>>(memsrc, obuf, membf, c_g1, c_b1);
    gemm_bt<1><<<dim3(323 * 4), 256, 0, stream>>>(membf, WmT, c_bm, qbuf, 41280, 512, 4);
    gemm_bt<1><<<dim3(323 * 4), 256, 0, stream>>>(qbuf, WmT, c_bm, obuf, 41280, 512, 4);
    ln_kernel<<<dim3(10320), 256, 0, stream>>>(membf, obuf, membf, c_g2, c_b2);
    memsrc = membf;
  }

  tanhmem_kernel<<<dim3(2641920 / 256), 256, 0, stream>>>(c_mem, qbuf, 2641920);
  // fused gate GEMM + gates: reads tanh(mem), Wmg(both halves), membf, c_mem;
  // writes next_memory (nmbf) + d_out directly. No gm round-trip.
  gemm_gates<<<dim3(323 * 8), 256, 0, stream>>>(qbuf, WmgT, c_bmg, gi, membf, c_mem,
                                                c_ib, c_fb, nmbf, d_out, flag, 41280);

  // fused K/V projection of next_memory: [41280][1024] = nmbf @ [Wk|Wv]
  gemm_bt<0><<<dim3(323 * 8), 256, 0, stream>>>(nmbf, WqkvT + (size_t)512 * 512, bkv,
                                                kvbuf, 41280, 1024, 8);
  attn2_mfma<<<dim3(256, 4), 256, 0, stream>>>(qkvbuf, kvbuf, kvbuf + 512, pacc, pml,
                                               1536, 1024);
  attn2_merge<<<dim3(8192), 256, 0, stream>>>(pacc, pml, d_out, flag);
}